// Round 7
// baseline (313.145 us; speedup 1.0000x reference)
//
#include <hip/hip_runtime.h>

typedef __attribute__((ext_vector_type(4))) float f32x4;
typedef __attribute__((ext_vector_type(8))) short s16x8;

__device__ __forceinline__ unsigned short f2bf(float f) {
  union { float f; unsigned int i; } x; x.f = f;
  unsigned int lsb = (x.i >> 16) & 1u;
  x.i += 0x7fffu + lsb;            // round-to-nearest-even
  return (unsigned short)(x.i >> 16);
}

__device__ __forceinline__ float bf2f(unsigned short u) {
  union { unsigned int i; float f; } x;
  x.i = ((unsigned int)u) << 16;
  return x.f;
}

// ---------------------------------------------------------------------------
// prep_w: W^T (n-major) bf16 weights + rope tables (all inputs f32).
// blocks 0..767: W1t[768][256] | 768..1023: Wo1t | 1024..1791: W2t
// 1792..2047: Wo2t | 2048: rope cos/sin [16][32] f32
// ---------------------------------------------------------------------------
__global__ void prep_w(const float* __restrict__ Wq1, const float* __restrict__ Wk1,
                       const float* __restrict__ Wv1, const float* __restrict__ Wo1,
                       const float* __restrict__ Wq2, const float* __restrict__ Wk2,
                       const float* __restrict__ Wv2, const float* __restrict__ Wo2,
                       unsigned short* __restrict__ W1t, unsigned short* __restrict__ Wo1t,
                       unsigned short* __restrict__ W2t, unsigned short* __restrict__ Wo2t,
                       float* __restrict__ ropeC, float* __restrict__ ropeS) {
  int blk = blockIdx.x, tid = threadIdx.x;
  if (blk < 768) {
    int n = blk, k = tid;
    const float* src = (n < 256) ? Wq1 : (n < 512 ? Wk1 : Wv1);
    W1t[n * 256 + k] = f2bf(src[k * 256 + (n & 255)]);
  } else if (blk < 1024) {
    int n = blk - 768, k = tid;
    Wo1t[n * 256 + k] = f2bf(Wo1[k * 256 + n]);
  } else if (blk < 1792) {
    int n = blk - 1024, k = tid;
    const float* src = (n < 256) ? Wq2 : (n < 512 ? Wk2 : Wv2);
    W2t[n * 256 + k] = f2bf(src[k * 256 + (n & 255)]);
  } else if (blk < 2048) {
    int n = blk - 1792, k = tid;
    Wo2t[n * 256 + k] = f2bf(Wo2[k * 256 + n]);
  } else {
    #pragma unroll
    for (int it = 0; it < 2; ++it) {
      int idx = it * 256 + tid;          // 512 entries: t(16) x d(32)
      int t = idx >> 5, d = idx & 31;
      // inv_freq: 10000^(-(d&~1)/32); interleaved repeat => pairs share angle
      float inv = exp2f(-13.287712379549449f * (float)(d & 30) * (1.0f / 32.0f));
      float ang = (float)t * inv;
      ropeC[idx] = cosf(ang);
      ropeS[idx] = sinf(ang);
    }
  }
}

// ---------------------------------------------------------------------------
// transpose_in: [b,c,t,h,w] f32 -> rows (b, h*32+w, t) of [256] f32.
// blocks 0..1023: x -> xt ; 1024..2047: mm -> mmt
// ---------------------------------------------------------------------------
__global__ __launch_bounds__(256) void transpose_in(
    const float* __restrict__ X, const float* __restrict__ MM,
    float* __restrict__ xt, float* __restrict__ mmt) {
  __shared__ float lds[32][257];
  int blk = blockIdx.x, tid = threadIdx.x;
  bool isX = blk < 1024;
  int idx = blk & 1023;
  int b = idx >> 9, t = (idx >> 5) & 15, h = idx & 31;
  const float* src = isX ? X : MM;
  float* dstp = isX ? xt : mmt;

  int w_ = tid & 31, cg8 = tid >> 5;
  size_t base = (size_t)b * 4194304 + (size_t)t * 1024 + (size_t)h * 32 + w_;
  #pragma unroll
  for (int itr = 0; itr < 32; ++itr) {
    int c = itr * 8 + cg8;
    lds[w_][c] = src[base + (size_t)c * 16384];
  }
  __syncthreads();
  size_t seqb = ((size_t)b * 1024 + (size_t)h * 32) * 16 + t;
  #pragma unroll
  for (int w2 = 0; w2 < 32; ++w2)
    dstp[(seqb + (size_t)w2 * 16) * 256 + tid] = lds[w2][tid];
}

// ---------------------------------------------------------------------------
// fused_stage: one block per (b,seq) = 16 tokens x 256 dims.  (f32 i/o)
//   LN -> qkv GEMM (bf16 MFMA) -> rope -> per-head attention -> out-proj
//   + f32 residual. cross=0: k,v from LN(srcQ). cross=1: k,v from LN(srcK).
// LDS = 63232 B.
// ---------------------------------------------------------------------------
__global__ __launch_bounds__(256) void fused_stage(
    const float* __restrict__ srcQ, const float* __restrict__ srcK,
    float* __restrict__ dst,
    const float* __restrict__ gq, const float* __restrict__ bq,
    const float* __restrict__ gk, const float* __restrict__ bk,
    const unsigned short* __restrict__ Wqkv, const unsigned short* __restrict__ Wo,
    const float* __restrict__ ropeC, const float* __restrict__ ropeS,
    const float* __restrict__ pbias, int cross) {
  __shared__ float rawQf[16 * 256];           // 16 KB: raw srcQ rows (LN in + residual)
  __shared__ unsigned short xnQ[16 * 272];    // 8.7 KB: LN'd Q rows; later aout
  __shared__ unsigned short xnK[16 * 272];    // 8.7 KB: LN'd K rows (cross)
  __shared__ unsigned short qkv[16 * 776];    // 24.8 KB: q|k|v rows
  __shared__ unsigned short ps[4][2][16][18]; // 4.6 KB: per-wave P store [key][query]

  int tid = threadIdx.x, lane = tid & 63, wv = tid >> 6;
  size_t r0 = (size_t)blockIdx.x * 16;
  int r = lane & 15, g = lane >> 4;

  // ---- Phase A: load raw Q rows (f32) ----
  {
    int row = tid >> 4, c0 = (tid & 15) * 16;
    const float* sp = srcQ + (r0 + row) * 256 + c0;
    f32x4* dp = (f32x4*)&rawQf[row * 256 + c0];
    dp[0] = *(const f32x4*)(sp);
    dp[1] = *(const f32x4*)(sp + 4);
    dp[2] = *(const f32x4*)(sp + 8);
    dp[3] = *(const f32x4*)(sp + 12);
  }
  __syncthreads();

  // ---- Phase A2: LayerNorm ----
  {
    int row = tid >> 4, l16 = tid & 15;
    float v[16], s = 0.f, q = 0.f;
    #pragma unroll
    for (int e = 0; e < 16; ++e) {
      v[e] = rawQf[row * 256 + l16 * 16 + e];
      s += v[e]; q += v[e] * v[e];
    }
    s += __shfl_xor(s, 1); q += __shfl_xor(q, 1);
    s += __shfl_xor(s, 2); q += __shfl_xor(q, 2);
    s += __shfl_xor(s, 4); q += __shfl_xor(q, 4);
    s += __shfl_xor(s, 8); q += __shfl_xor(q, 8);
    float mu = s * (1.f / 256.f);
    float var = q * (1.f / 256.f) - mu * mu;
    float rs = rsqrtf(fmaxf(var, 0.f) + 1e-5f);
    #pragma unroll
    for (int e = 0; e < 16; ++e) {
      int c = l16 * 16 + e;
      xnQ[row * 272 + c] = f2bf((v[e] - mu) * rs * gq[c] + bq[c]);
    }
    if (cross) {   // LN of K-source rows, straight from global into registers
      const float* kp = srcK + (r0 + row) * 256 + l16 * 16;
      float vk[16], sk = 0.f, qk = 0.f;
      #pragma unroll
      for (int e = 0; e < 16; ++e) {
        vk[e] = kp[e];
        sk += vk[e]; qk += vk[e] * vk[e];
      }
      sk += __shfl_xor(sk, 1); qk += __shfl_xor(qk, 1);
      sk += __shfl_xor(sk, 2); qk += __shfl_xor(qk, 2);
      sk += __shfl_xor(sk, 4); qk += __shfl_xor(qk, 4);
      sk += __shfl_xor(sk, 8); qk += __shfl_xor(qk, 8);
      float muk = sk * (1.f / 256.f);
      float vark = qk * (1.f / 256.f) - muk * muk;
      float rsk = rsqrtf(fmaxf(vark, 0.f) + 1e-5f);
      #pragma unroll
      for (int e = 0; e < 16; ++e) {
        int c = l16 * 16 + e;
        xnK[row * 272 + c] = f2bf((vk[e] - muk) * rsk * gk[c] + bk[c]);
      }
    }
  }
  __syncthreads();

  const unsigned short* xnKp = cross ? xnK : xnQ;

  // ---- Phase B: qkv = xn @ Wqkv^T, rope(q,k), q-scale ----
  for (int it = 0; it < 12; ++it) {
    int n0 = (wv * 12 + it) * 16;                        // 48 n-tiles over 768
    const unsigned short* xs = (n0 < 256) ? xnQ : xnKp;  // q from xnQ; k,v from xnK
    f32x4 acc = {};
    #pragma unroll
    for (int kc = 0; kc < 8; ++kc) {
      s16x8 af = *(const s16x8*)&xs[r * 272 + kc * 32 + g * 8];
      s16x8 bf = *(const s16x8*)&Wqkv[(size_t)(n0 + r) * 256 + kc * 32 + g * 8];
      acc = __builtin_amdgcn_mfma_f32_16x16x32_bf16(af, bf, acc, 0, 0, 0);
    }
    int n = n0 + r;                    // C col = lane&15 [m89]
    if (n0 < 512) {                    // rope on q,k
      float scale = (n0 < 256) ? 0.17677669529663687f : 1.0f;
      int d = n & 31;
      #pragma unroll
      for (int rr = 0; rr < 4; ++rr) {
        float part = __shfl_xor(acc[rr], 1);   // pair partner col n^1 (same token)
        int tok = 4 * g + rr;                  // C row = 4*(lane>>4)+reg
        float cc = ropeC[tok * 32 + d], ss = ropeS[tok * 32 + d];
        float val = (n & 1) ? (acc[rr] * cc + part * ss)
                            : (acc[rr] * cc - part * ss);
        qkv[tok * 776 + n] = f2bf(val * scale);
      }
    } else {                           // v: plain
      #pragma unroll
      for (int rr = 0; rr < 4; ++rr)
        qkv[(4 * g + rr) * 776 + n] = f2bf(acc[rr]);
    }
  }
  __syncthreads();

  // ---- Phase C1: sim^T = mfma(K, Q); softmax over keys in-register ----
  for (int hs = 0; hs < 2; ++hs) {
    int h = wv * 2 + hs;               // 2 heads per wave
    s16x8 kf = *(const s16x8*)&qkv[r * 776 + 256 + h * 32 + g * 8];
    s16x8 qf = *(const s16x8*)&qkv[r * 776 +       h * 32 + g * 8];
    f32x4 zero = {};
    f32x4 st = __builtin_amdgcn_mfma_f32_16x16x32_bf16(kf, qf, zero, 0, 0, 0);
    // lane holds sim[query=r][key=4g+rr]
    float p0 = st[0] + pbias[h * 256 + r * 16 + 4 * g + 0];
    float p1 = st[1] + pbias[h * 256 + r * 16 + 4 * g + 1];
    float p2 = st[2] + pbias[h * 256 + r * 16 + 4 * g + 2];
    float p3 = st[3] + pbias[h * 256 + r * 16 + 4 * g + 3];
    float mx = fmaxf(fmaxf(p0, p1), fmaxf(p2, p3));
    mx = fmaxf(mx, __shfl_xor(mx, 16));
    mx = fmaxf(mx, __shfl_xor(mx, 32));
    p0 = __expf(p0 - mx); p1 = __expf(p1 - mx);
    p2 = __expf(p2 - mx); p3 = __expf(p3 - mx);
    float sm = p0 + p1 + p2 + p3;
    sm += __shfl_xor(sm, 16);
    sm += __shfl_xor(sm, 32);
    float inv = 1.0f / sm;
    ps[wv][hs][4 * g + 0][r] = f2bf(p0 * inv);
    ps[wv][hs][4 * g + 1][r] = f2bf(p1 * inv);
    ps[wv][hs][4 * g + 2][r] = f2bf(p2 * inv);
    ps[wv][hs][4 * g + 3][r] = f2bf(p3 * inv);
  }
  __syncthreads();

  // ---- Phase C2: aout = P @ V (keys zero-padded 16->32); aout aliases xnQ ----
  unsigned short* aout = xnQ;          // xnQ dead after Phase B
  for (int hs = 0; hs < 2; ++hs) {
    int h = wv * 2 + hs;
    #pragma unroll
    for (int dt = 0; dt < 2; ++dt) {
      s16x8 pa, bv;
      #pragma unroll
      for (int e = 0; e < 8; ++e) {
        int j = 8 * g + e;
        int jc = (j < 16) ? j : 0;
        pa[e] = (j < 16) ? (short)ps[wv][hs][jc][r] : (short)0;
        bv[e] = (short)qkv[jc * 776 + 512 + h * 32 + dt * 16 + r];
      }
      f32x4 zero = {};
      f32x4 o = __builtin_amdgcn_mfma_f32_16x16x32_bf16(pa, bv, zero, 0, 0, 0);
      #pragma unroll
      for (int rr = 0; rr < 4; ++rr)
        aout[(4 * g + rr) * 272 + h * 32 + dt * 16 + r] = f2bf(o[rr]);
    }
  }
  __syncthreads();

  // ---- Phase D: dst = aout @ Wo^T + f32 residual ----
  for (int it = 0; it < 4; ++it) {
    int n0 = (wv * 4 + it) * 16;       // 16 n-tiles over 256
    f32x4 acc = {};
    #pragma unroll
    for (int kc = 0; kc < 8; ++kc) {
      s16x8 af = *(const s16x8*)&aout[r * 272 + kc * 32 + g * 8];
      s16x8 bf = *(const s16x8*)&Wo[(size_t)(n0 + r) * 256 + kc * 32 + g * 8];
      acc = __builtin_amdgcn_mfma_f32_16x16x32_bf16(af, bf, acc, 0, 0, 0);
    }
    #pragma unroll
    for (int rr = 0; rr < 4; ++rr) {
      int tok = 4 * g + rr, n = n0 + r;
      dst[(r0 + tok) * 256 + n] = acc[rr] + rawQf[tok * 256 + n];
    }
  }
}

// ---------------------------------------------------------------------------
// transpose_out: rows (b,hw,t)[256] f32 -> [b,c,t,h,w] f32
// ---------------------------------------------------------------------------
__global__ __launch_bounds__(256) void transpose_out(const float* __restrict__ xs2,
                                                     float* __restrict__ outp) {
  __shared__ float lds[32][257];
  int blk = blockIdx.x, tid = threadIdx.x;
  int b = blk >> 9, t = (blk >> 5) & 15, h = blk & 31;
  size_t seqb = ((size_t)b * 1024 + (size_t)h * 32) * 16 + t;
  #pragma unroll
  for (int w2 = 0; w2 < 32; ++w2)
    lds[w2][tid] = xs2[(seqb + (size_t)w2 * 16) * 256 + tid];
  __syncthreads();
  int w_ = tid & 31, cg8 = tid >> 5;
  size_t base = (size_t)b * 4194304 + (size_t)t * 1024 + (size_t)h * 32 + w_;
  #pragma unroll
  for (int itr = 0; itr < 32; ++itr) {
    int c = itr * 8 + cg8;
    outp[base + (size_t)c * 16384] = lds[w_][c];
  }
}

// ---------------------------------------------------------------------------
extern "C" void kernel_launch(void* const* d_in, const int* in_sizes, int n_in,
                              void* d_out, int out_size, void* d_ws, size_t ws_size,
                              hipStream_t stream) {
  const float* x   = (const float*)d_in[0];
  const float* mm  = (const float*)d_in[1];
  const float* pb  = (const float*)d_in[2];
  const float* g1  = (const float*)d_in[3];
  const float* b1  = (const float*)d_in[4];
  const float* Wq1 = (const float*)d_in[5];
  const float* Wk1 = (const float*)d_in[6];
  const float* Wv1 = (const float*)d_in[7];
  const float* Wo1 = (const float*)d_in[8];
  const float* g2  = (const float*)d_in[9];
  const float* b2  = (const float*)d_in[10];
  const float* cg  = (const float*)d_in[11];
  const float* cb  = (const float*)d_in[12];
  const float* Wq2 = (const float*)d_in[13];
  const float* Wk2 = (const float*)d_in[14];
  const float* Wv2 = (const float*)d_in[15];
  const float* Wo2 = (const float*)d_in[16];

  // Workspace (68.16 MB):
  //   [0, 1052672)              W1t | Wo1t | W2t | Wo2t (bf16) + rope tables
  //   xt  [1052672,  +33.55MB)  f32 rows of x  -> (stage-2 output) xs2
  //   mmt [34607104, +33.55MB)  f32 rows of mm
  // d_out (f32 [32768][256] = 33.55MB) holds xs1 between stages; the final
  // transpose overwrites it with [b,c,t,h,w] f32.
  char* ws = (char*)d_ws;
  unsigned short* W1t  = (unsigned short*)(ws + 0);
  unsigned short* Wo1t = (unsigned short*)(ws + 393216);
  unsigned short* W2t  = (unsigned short*)(ws + 524288);
  unsigned short* Wo2t = (unsigned short*)(ws + 917504);
  float* ropeC         = (float*)(ws + 1048576);
  float* ropeS         = (float*)(ws + 1050624);
  float* xt            = (float*)(ws + 1052672);
  float* mmt           = (float*)(ws + 34607104);
  float* xs1           = (float*)d_out;
  float* outp          = (float*)d_out;

  prep_w<<<2049, 256, 0, stream>>>(Wq1, Wk1, Wv1, Wo1, Wq2, Wk2, Wv2, Wo2,
                                   W1t, Wo1t, W2t, Wo2t, ropeC, ropeS);
  transpose_in<<<2048, 256, 0, stream>>>(x, mm, xt, mmt);
  // stage 1: self attention (q,k,v from LN(x; g1,b1)); xs1 -> d_out
  fused_stage<<<2048, 256, 0, stream>>>(xt, xt, xs1, g1, b1, g1, b1,
                                        W1t, Wo1t, ropeC, ropeS, pb, 0);
  // stage 2: cross attention (q from LN(xs1; g2,b2), k,v from LN(mm; cg,cb))
  fused_stage<<<2048, 256, 0, stream>>>(xs1, mmt, xt, g2, b2, cg, cb,
                                        W2t, Wo2t, ropeC, ropeS, pb, 1);
  transpose_out<<<1024, 256, 0, stream>>>(xt, outp);
}

// Round 8
// 305.642 us; speedup vs baseline: 1.0245x; 1.0245x over previous
//
#include <hip/hip_runtime.h>

typedef __attribute__((ext_vector_type(4))) float f32x4;
typedef __attribute__((ext_vector_type(8))) short s16x8;

__device__ __forceinline__ unsigned short f2bf(float f) {
  union { float f; unsigned int i; } x; x.f = f;
  unsigned int lsb = (x.i >> 16) & 1u;
  x.i += 0x7fffu + lsb;            // round-to-nearest-even
  return (unsigned short)(x.i >> 16);
}

__device__ __forceinline__ float bf2f(unsigned short u) {
  union { unsigned int i; float f; } x;
  x.i = ((unsigned int)u) << 16;
  return x.f;
}

// ---------------------------------------------------------------------------
// prep_w: W^T (n-major) bf16 weights + rope tables (all inputs f32).
// blocks 0..767: W1t[768][256] | 768..1023: Wo1t | 1024..1791: W2t
// 1792..2047: Wo2t | 2048: rope cos/sin [16][32] f32
// ---------------------------------------------------------------------------
__global__ void prep_w(const float* __restrict__ Wq1, const float* __restrict__ Wk1,
                       const float* __restrict__ Wv1, const float* __restrict__ Wo1,
                       const float* __restrict__ Wq2, const float* __restrict__ Wk2,
                       const float* __restrict__ Wv2, const float* __restrict__ Wo2,
                       unsigned short* __restrict__ W1t, unsigned short* __restrict__ Wo1t,
                       unsigned short* __restrict__ W2t, unsigned short* __restrict__ Wo2t,
                       float* __restrict__ ropeC, float* __restrict__ ropeS) {
  int blk = blockIdx.x, tid = threadIdx.x;
  if (blk < 768) {
    int n = blk, k = tid;
    const float* src = (n < 256) ? Wq1 : (n < 512 ? Wk1 : Wv1);
    W1t[n * 256 + k] = f2bf(src[k * 256 + (n & 255)]);
  } else if (blk < 1024) {
    int n = blk - 768, k = tid;
    Wo1t[n * 256 + k] = f2bf(Wo1[k * 256 + n]);
  } else if (blk < 1792) {
    int n = blk - 1024, k = tid;
    const float* src = (n < 256) ? Wq2 : (n < 512 ? Wk2 : Wv2);
    W2t[n * 256 + k] = f2bf(src[k * 256 + (n & 255)]);
  } else if (blk < 2048) {
    int n = blk - 1792, k = tid;
    Wo2t[n * 256 + k] = f2bf(Wo2[k * 256 + n]);
  } else {
    #pragma unroll
    for (int it = 0; it < 2; ++it) {
      int idx = it * 256 + tid;          // 512 entries: t(16) x d(32)
      int t = idx >> 5, d = idx & 31;
      // inv_freq: 10000^(-(d&~1)/32); interleaved repeat => pairs share angle
      float inv = exp2f(-13.287712379549449f * (float)(d & 30) * (1.0f / 32.0f));
      float ang = (float)t * inv;
      ropeC[idx] = cosf(ang);
      ropeS[idx] = sinf(ang);
    }
  }
}

// ---------------------------------------------------------------------------
// transpose_in: [b,c,t,h,w] f32 -> rows (b, h*32+w, t) of [256] f32.
// blocks 0..1023: x -> xt ; 1024..2047: mm -> mmt
// ---------------------------------------------------------------------------
__global__ __launch_bounds__(256) void transpose_in(
    const float* __restrict__ X, const float* __restrict__ MM,
    float* __restrict__ xt, float* __restrict__ mmt) {
  __shared__ float lds[32][257];
  int blk = blockIdx.x, tid = threadIdx.x;
  bool isX = blk < 1024;
  int idx = blk & 1023;
  int b = idx >> 9, t = (idx >> 5) & 15, h = idx & 31;
  const float* src = isX ? X : MM;
  float* dstp = isX ? xt : mmt;

  int w_ = tid & 31, cg8 = tid >> 5;
  size_t base = (size_t)b * 4194304 + (size_t)t * 1024 + (size_t)h * 32 + w_;
  #pragma unroll
  for (int itr = 0; itr < 32; ++itr) {
    int c = itr * 8 + cg8;
    lds[w_][c] = src[base + (size_t)c * 16384];
  }
  __syncthreads();
  size_t seqb = ((size_t)b * 1024 + (size_t)h * 32) * 16 + t;
  #pragma unroll
  for (int w2 = 0; w2 < 32; ++w2)
    dstp[(seqb + (size_t)w2 * 16) * 256 + tid] = lds[w2][tid];
}

// ---------------------------------------------------------------------------
// fused_stage: one block per (b,seq) = 16 tokens x 256 dims.  (f32 i/o)
//   reg-LN -> qkv GEMM (bf16 MFMA, split-acc) -> rope -> per-head attention
//   -> out-proj + f32 residual (re-read from global).
// cross=0: k,v from LN(srcQ). cross=1: k,v from LN(srcK).
// LDS = 45.8 KB -> 3 blocks/CU (was 63.5 KB -> 2).
// ---------------------------------------------------------------------------
__global__ __launch_bounds__(256) void fused_stage(
    const float* __restrict__ srcQ, const float* __restrict__ srcK,
    float* __restrict__ dst,
    const float* __restrict__ gq, const float* __restrict__ bq,
    const float* __restrict__ gk, const float* __restrict__ bk,
    const unsigned short* __restrict__ Wqkv, const unsigned short* __restrict__ Wo,
    const float* __restrict__ ropeC, const float* __restrict__ ropeS,
    const float* __restrict__ pbias, int cross) {
  __shared__ unsigned short xnQ[16 * 272];    // 8.7 KB: LN'd Q rows; later aout
  __shared__ unsigned short xnK[16 * 272];    // 8.7 KB: LN'd K rows (cross)
  __shared__ unsigned short qkv[16 * 776];    // 24.8 KB: q|k|v rows
  __shared__ unsigned short ps[4][2][16][18]; // 2.3 KB: per-wave P store [key][query]

  int tid = threadIdx.x, lane = tid & 63, wv = tid >> 6;
  size_t r0 = (size_t)blockIdx.x * 16;
  int r = lane & 15, g = lane >> 4;

  // ---- Phase A: register LayerNorm straight from global ----
  {
    int row = tid >> 4, l16 = tid & 15;
    const float* sp = srcQ + (r0 + row) * 256 + l16 * 16;
    f32x4 v0 = *(const f32x4*)(sp);
    f32x4 v1 = *(const f32x4*)(sp + 4);
    f32x4 v2 = *(const f32x4*)(sp + 8);
    f32x4 v3 = *(const f32x4*)(sp + 12);
    float s = 0.f, q = 0.f;
    #pragma unroll
    for (int e = 0; e < 4; ++e) {
      s += v0[e] + v1[e] + v2[e] + v3[e];
      q += v0[e]*v0[e] + v1[e]*v1[e] + v2[e]*v2[e] + v3[e]*v3[e];
    }
    s += __shfl_xor(s, 1); q += __shfl_xor(q, 1);
    s += __shfl_xor(s, 2); q += __shfl_xor(q, 2);
    s += __shfl_xor(s, 4); q += __shfl_xor(q, 4);
    s += __shfl_xor(s, 8); q += __shfl_xor(q, 8);
    float mu = s * (1.f / 256.f);
    float var = q * (1.f / 256.f) - mu * mu;
    float rs = rsqrtf(fmaxf(var, 0.f) + 1e-5f);
    #pragma unroll
    for (int e = 0; e < 16; ++e) {
      int c = l16 * 16 + e;
      float v = (e < 4) ? v0[e] : (e < 8) ? v1[e - 4] : (e < 12) ? v2[e - 8] : v3[e - 12];
      xnQ[row * 272 + c] = f2bf((v - mu) * rs * gq[c] + bq[c]);
    }
    if (cross) {
      const float* kp = srcK + (r0 + row) * 256 + l16 * 16;
      f32x4 k0 = *(const f32x4*)(kp);
      f32x4 k1 = *(const f32x4*)(kp + 4);
      f32x4 k2 = *(const f32x4*)(kp + 8);
      f32x4 k3 = *(const f32x4*)(kp + 12);
      float sk = 0.f, qk = 0.f;
      #pragma unroll
      for (int e = 0; e < 4; ++e) {
        sk += k0[e] + k1[e] + k2[e] + k3[e];
        qk += k0[e]*k0[e] + k1[e]*k1[e] + k2[e]*k2[e] + k3[e]*k3[e];
      }
      sk += __shfl_xor(sk, 1); qk += __shfl_xor(qk, 1);
      sk += __shfl_xor(sk, 2); qk += __shfl_xor(qk, 2);
      sk += __shfl_xor(sk, 4); qk += __shfl_xor(qk, 4);
      sk += __shfl_xor(sk, 8); qk += __shfl_xor(qk, 8);
      float muk = sk * (1.f / 256.f);
      float vark = qk * (1.f / 256.f) - muk * muk;
      float rsk = rsqrtf(fmaxf(vark, 0.f) + 1e-5f);
      #pragma unroll
      for (int e = 0; e < 16; ++e) {
        int c = l16 * 16 + e;
        float v = (e < 4) ? k0[e] : (e < 8) ? k1[e - 4] : (e < 12) ? k2[e - 8] : k3[e - 12];
        xnK[row * 272 + c] = f2bf((v - muk) * rsk * gk[c] + bk[c]);
      }
    }
  }
  __syncthreads();

  const unsigned short* xnKp = cross ? xnK : xnQ;

  // ---- Phase B: qkv = xn @ Wqkv^T (split-acc), rope(q,k), q-scale ----
  #pragma unroll 2
  for (int it = 0; it < 12; ++it) {
    int n0 = (wv * 12 + it) * 16;                        // 48 n-tiles over 768
    const unsigned short* xs = (n0 < 256) ? xnQ : xnKp;  // q from xnQ; k,v from xnK
    f32x4 acc0 = {}, acc1 = {};
    #pragma unroll
    for (int kc = 0; kc < 4; ++kc) {
      s16x8 af0 = *(const s16x8*)&xs[r * 272 + kc * 32 + g * 8];
      s16x8 bf0 = *(const s16x8*)&Wqkv[(size_t)(n0 + r) * 256 + kc * 32 + g * 8];
      acc0 = __builtin_amdgcn_mfma_f32_16x16x32_bf16(af0, bf0, acc0, 0, 0, 0);
      s16x8 af1 = *(const s16x8*)&xs[r * 272 + (kc + 4) * 32 + g * 8];
      s16x8 bf1 = *(const s16x8*)&Wqkv[(size_t)(n0 + r) * 256 + (kc + 4) * 32 + g * 8];
      acc1 = __builtin_amdgcn_mfma_f32_16x16x32_bf16(af1, bf1, acc1, 0, 0, 0);
    }
    f32x4 acc = acc0 + acc1;
    int n = n0 + r;                    // C col = lane&15 [m89]
    if (n0 < 512) {                    // rope on q,k
      float scale = (n0 < 256) ? 0.17677669529663687f : 1.0f;
      int d = n & 31;
      #pragma unroll
      for (int rr = 0; rr < 4; ++rr) {
        float part = __shfl_xor(acc[rr], 1);   // pair partner col n^1 (same token)
        int tok = 4 * g + rr;                  // C row = 4*(lane>>4)+reg
        float cc = ropeC[tok * 32 + d], ss = ropeS[tok * 32 + d];
        float val = (n & 1) ? (acc[rr] * cc + part * ss)
                            : (acc[rr] * cc - part * ss);
        qkv[tok * 776 + n] = f2bf(val * scale);
      }
    } else {                           // v: plain
      #pragma unroll
      for (int rr = 0; rr < 4; ++rr)
        qkv[(4 * g + rr) * 776 + n] = f2bf(acc[rr]);
    }
  }
  __syncthreads();

  // ---- Phase C: per-head attention (ps is same-wave: no barrier needed) ----
  unsigned short* aout = xnQ;          // xnQ dead after Phase B
  for (int hs = 0; hs < 2; ++hs) {
    int h = wv * 2 + hs;               // 2 heads per wave
    s16x8 kf = *(const s16x8*)&qkv[r * 776 + 256 + h * 32 + g * 8];
    s16x8 qf = *(const s16x8*)&qkv[r * 776 +       h * 32 + g * 8];
    f32x4 zero = {};
    f32x4 st = __builtin_amdgcn_mfma_f32_16x16x32_bf16(kf, qf, zero, 0, 0, 0);
    // lane holds sim[query=r][key=4g+rr]
    f32x4 bb = *(const f32x4*)&pbias[h * 256 + r * 16 + 4 * g];
    float p0 = st[0] + bb[0], p1 = st[1] + bb[1];
    float p2 = st[2] + bb[2], p3 = st[3] + bb[3];
    float mx = fmaxf(fmaxf(p0, p1), fmaxf(p2, p3));
    mx = fmaxf(mx, __shfl_xor(mx, 16));
    mx = fmaxf(mx, __shfl_xor(mx, 32));
    p0 = __expf(p0 - mx); p1 = __expf(p1 - mx);
    p2 = __expf(p2 - mx); p3 = __expf(p3 - mx);
    float sm = p0 + p1 + p2 + p3;
    sm += __shfl_xor(sm, 16);
    sm += __shfl_xor(sm, 32);
    float inv = 1.0f / sm;
    ps[wv][hs][4 * g + 0][r] = f2bf(p0 * inv);
    ps[wv][hs][4 * g + 1][r] = f2bf(p1 * inv);
    ps[wv][hs][4 * g + 2][r] = f2bf(p2 * inv);
    ps[wv][hs][4 * g + 3][r] = f2bf(p3 * inv);

    // aout = P @ V (keys zero-padded 16->32); same-wave ps read
    #pragma unroll
    for (int dt = 0; dt < 2; ++dt) {
      s16x8 pa, bv;
      #pragma unroll
      for (int e = 0; e < 8; ++e) {
        int j = 8 * g + e;
        int jc = (j < 16) ? j : 0;
        pa[e] = (j < 16) ? (short)ps[wv][hs][jc][r] : (short)0;
        bv[e] = (short)qkv[jc * 776 + 512 + h * 32 + dt * 16 + r];
      }
      f32x4 o = __builtin_amdgcn_mfma_f32_16x16x32_bf16(pa, bv, zero, 0, 0, 0);
      #pragma unroll
      for (int rr = 0; rr < 4; ++rr)
        aout[(4 * g + rr) * 272 + h * 32 + dt * 16 + r] = f2bf(o[rr]);
    }
  }
  __syncthreads();

  // ---- Phase D: dst = aout @ Wo^T (split-acc) + f32 residual from global ----
  #pragma unroll 2
  for (int it = 0; it < 4; ++it) {
    int n0 = (wv * 4 + it) * 16;       // 16 n-tiles over 256
    f32x4 acc0 = {}, acc1 = {};
    #pragma unroll
    for (int kc = 0; kc < 4; ++kc) {
      s16x8 af0 = *(const s16x8*)&aout[r * 272 + kc * 32 + g * 8];
      s16x8 bf0 = *(const s16x8*)&Wo[(size_t)(n0 + r) * 256 + kc * 32 + g * 8];
      acc0 = __builtin_amdgcn_mfma_f32_16x16x32_bf16(af0, bf0, acc0, 0, 0, 0);
      s16x8 af1 = *(const s16x8*)&aout[r * 272 + (kc + 4) * 32 + g * 8];
      s16x8 bf1 = *(const s16x8*)&Wo[(size_t)(n0 + r) * 256 + (kc + 4) * 32 + g * 8];
      acc1 = __builtin_amdgcn_mfma_f32_16x16x32_bf16(af1, bf1, acc1, 0, 0, 0);
    }
    f32x4 acc = acc0 + acc1;
    #pragma unroll
    for (int rr = 0; rr < 4; ++rr) {
      int tok = 4 * g + rr, n = n0 + r;
      size_t idx = (r0 + tok) * 256 + n;
      dst[idx] = acc[rr] + srcQ[idx];
    }
  }
}

// ---------------------------------------------------------------------------
// transpose_out: rows (b,hw,t)[256] f32 -> [b,c,t,h,w] f32
// ---------------------------------------------------------------------------
__global__ __launch_bounds__(256) void transpose_out(const float* __restrict__ xs2,
                                                     float* __restrict__ outp) {
  __shared__ float lds[32][257];
  int blk = blockIdx.x, tid = threadIdx.x;
  int b = blk >> 9, t = (blk >> 5) & 15, h = blk & 31;
  size_t seqb = ((size_t)b * 1024 + (size_t)h * 32) * 16 + t;
  #pragma unroll
  for (int w2 = 0; w2 < 32; ++w2)
    lds[w2][tid] = xs2[(seqb + (size_t)w2 * 16) * 256 + tid];
  __syncthreads();
  int w_ = tid & 31, cg8 = tid >> 5;
  size_t base = (size_t)b * 4194304 + (size_t)t * 1024 + (size_t)h * 32 + w_;
  #pragma unroll
  for (int itr = 0; itr < 32; ++itr) {
    int c = itr * 8 + cg8;
    outp[base + (size_t)c * 16384] = lds[w_][c];
  }
}

// ---------------------------------------------------------------------------
extern "C" void kernel_launch(void* const* d_in, const int* in_sizes, int n_in,
                              void* d_out, int out_size, void* d_ws, size_t ws_size,
                              hipStream_t stream) {
  const float* x   = (const float*)d_in[0];
  const float* mm  = (const float*)d_in[1];
  const float* pb  = (const float*)d_in[2];
  const float* g1  = (const float*)d_in[3];
  const float* b1  = (const float*)d_in[4];
  const float* Wq1 = (const float*)d_in[5];
  const float* Wk1 = (const float*)d_in[6];
  const float* Wv1 = (const float*)d_in[7];
  const float* Wo1 = (const float*)d_in[8];
  const float* g2  = (const float*)d_in[9];
  const float* b2  = (const float*)d_in[10];
  const float* cg  = (const float*)d_in[11];
  const float* cb  = (const float*)d_in[12];
  const float* Wq2 = (const float*)d_in[13];
  const float* Wk2 = (const float*)d_in[14];
  const float* Wv2 = (const float*)d_in[15];
  const float* Wo2 = (const float*)d_in[16];

  // Workspace (68.16 MB):
  //   [0, 1052672)              W1t | Wo1t | W2t | Wo2t (bf16) + rope tables
  //   xt  [1052672,  +33.55MB)  f32 rows of x  -> (stage-2 output) xs2
  //   mmt [34607104, +33.55MB)  f32 rows of mm
  // d_out (f32 [32768][256]) holds xs1 between stages; final transpose
  // overwrites it with [b,c,t,h,w] f32.
  char* ws = (char*)d_ws;
  unsigned short* W1t  = (unsigned short*)(ws + 0);
  unsigned short* Wo1t = (unsigned short*)(ws + 393216);
  unsigned short* W2t  = (unsigned short*)(ws + 524288);
  unsigned short* Wo2t = (unsigned short*)(ws + 917504);
  float* ropeC         = (float*)(ws + 1048576);
  float* ropeS         = (float*)(ws + 1050624);
  float* xt            = (float*)(ws + 1052672);
  float* mmt           = (float*)(ws + 34607104);
  float* xs1           = (float*)d_out;
  float* outp          = (float*)d_out;

  prep_w<<<2049, 256, 0, stream>>>(Wq1, Wk1, Wv1, Wo1, Wq2, Wk2, Wv2, Wo2,
                                   W1t, Wo1t, W2t, Wo2t, ropeC, ropeS);
  transpose_in<<<2048, 256, 0, stream>>>(x, mm, xt, mmt);
  // stage 1: self attention (q,k,v from LN(x; g1,b1)); xs1 -> d_out
  fused_stage<<<2048, 256, 0, stream>>>(xt, xt, xs1, g1, b1, g1, b1,
                                        W1t, Wo1t, ropeC, ropeS, pb, 0);
  // stage 2: cross attention (q from LN(xs1; g2,b2), k,v from LN(mm; cg,cb))
  fused_stage<<<2048, 256, 0, stream>>>(xs1, mmt, xt, g2, b2, cg, cb,
                                        W2t, Wo2t, ropeC, ropeS, pb, 1);
  transpose_out<<<1024, 256, 0, stream>>>(xt, outp);
}

// Round 9
// 218.244 us; speedup vs baseline: 1.4348x; 1.4005x over previous
//
#include <hip/hip_runtime.h>

typedef __attribute__((ext_vector_type(4))) float f32x4;
typedef __attribute__((ext_vector_type(8))) short s16x8;

__device__ __forceinline__ unsigned short f2bf(float f) {
  union { float f; unsigned int i; } x; x.f = f;
  unsigned int lsb = (x.i >> 16) & 1u;
  x.i += 0x7fffu + lsb;            // round-to-nearest-even
  return (unsigned short)(x.i >> 16);
}

__device__ __forceinline__ float bf2f(unsigned short u) {
  union { unsigned int i; float f; } x;
  x.i = ((unsigned int)u) << 16;
  return x.f;
}

__device__ __forceinline__ void gload_lds16(const void* gsrc, void* ldst) {
  __builtin_amdgcn_global_load_lds(
      (const __attribute__((address_space(1))) void*)gsrc,
      (__attribute__((address_space(3))) void*)ldst, 16, 0, 0);
}

// ---------------------------------------------------------------------------
// prep_w: W^T (n-major) bf16 weights + rope tables (all inputs f32).
// ---------------------------------------------------------------------------
__global__ void prep_w(const float* __restrict__ Wq1, const float* __restrict__ Wk1,
                       const float* __restrict__ Wv1, const float* __restrict__ Wo1,
                       const float* __restrict__ Wq2, const float* __restrict__ Wk2,
                       const float* __restrict__ Wv2, const float* __restrict__ Wo2,
                       unsigned short* __restrict__ W1t, unsigned short* __restrict__ Wo1t,
                       unsigned short* __restrict__ W2t, unsigned short* __restrict__ Wo2t,
                       float* __restrict__ ropeC, float* __restrict__ ropeS) {
  int blk = blockIdx.x, tid = threadIdx.x;
  if (blk < 768) {
    int n = blk, k = tid;
    const float* src = (n < 256) ? Wq1 : (n < 512 ? Wk1 : Wv1);
    W1t[n * 256 + k] = f2bf(src[k * 256 + (n & 255)]);
  } else if (blk < 1024) {
    int n = blk - 768, k = tid;
    Wo1t[n * 256 + k] = f2bf(Wo1[k * 256 + n]);
  } else if (blk < 1792) {
    int n = blk - 1024, k = tid;
    const float* src = (n < 256) ? Wq2 : (n < 512 ? Wk2 : Wv2);
    W2t[n * 256 + k] = f2bf(src[k * 256 + (n & 255)]);
  } else if (blk < 2048) {
    int n = blk - 1792, k = tid;
    Wo2t[n * 256 + k] = f2bf(Wo2[k * 256 + n]);
  } else {
    #pragma unroll
    for (int it = 0; it < 2; ++it) {
      int idx = it * 256 + tid;          // 512 entries: t(16) x d(32)
      int t = idx >> 5, d = idx & 31;
      float inv = exp2f(-13.287712379549449f * (float)(d & 30) * (1.0f / 32.0f));
      float ang = (float)t * inv;
      ropeC[idx] = cosf(ang);
      ropeS[idx] = sinf(ang);
    }
  }
}

// ---------------------------------------------------------------------------
// transpose_in: [b,c,t,h,w] f32 -> rows (b, h*32+w, t) of [256].
// outBf=1: write bf16; else f32. blocks 0..1023: x; 1024..2047: mm.
// ---------------------------------------------------------------------------
__global__ __launch_bounds__(256) void transpose_in(
    const float* __restrict__ X, const float* __restrict__ MM,
    void* __restrict__ xtv, void* __restrict__ mmtv, int outBf) {
  __shared__ float lds[32][257];
  int blk = blockIdx.x, tid = threadIdx.x;
  bool isX = blk < 1024;
  int idx = blk & 1023;
  int b = idx >> 9, t = (idx >> 5) & 15, h = idx & 31;
  const float* src = isX ? X : MM;

  int w_ = tid & 31, cg8 = tid >> 5;
  size_t base = (size_t)b * 4194304 + (size_t)t * 1024 + (size_t)h * 32 + w_;
  #pragma unroll
  for (int itr = 0; itr < 32; ++itr) {
    int c = itr * 8 + cg8;
    lds[w_][c] = src[base + (size_t)c * 16384];
  }
  __syncthreads();
  size_t seqb = ((size_t)b * 1024 + (size_t)h * 32) * 16 + t;
  if (outBf) {
    unsigned short* dstp = (unsigned short*)(isX ? xtv : mmtv);
    #pragma unroll
    for (int w2 = 0; w2 < 32; ++w2)
      dstp[(seqb + (size_t)w2 * 16) * 256 + tid] = f2bf(lds[w2][tid]);
  } else {
    float* dstp = (float*)(isX ? xtv : mmtv);
    #pragma unroll
    for (int w2 = 0; w2 < 32; ++w2)
      dstp[(seqb + (size_t)w2 * 16) * 256 + tid] = lds[w2][tid];
  }
}

// ---------------------------------------------------------------------------
// ln_rows: rowwise LayerNorm over 256; src f32 or bf16 rows -> bf16 rows.
// grid 2048: 16 rows/block; thread (row=tid>>4, l16=tid&15) — verified pattern.
// ---------------------------------------------------------------------------
__global__ __launch_bounds__(256) void ln_rows(
    const void* __restrict__ srcv, const float* __restrict__ gw,
    const float* __restrict__ bw, unsigned short* __restrict__ dst, int srcF32) {
  int tid = threadIdx.x;
  size_t row = (size_t)blockIdx.x * 16 + (tid >> 4);
  int l16 = tid & 15;
  float v[16], s = 0.f, q = 0.f;
  if (srcF32) {
    const float* sp = (const float*)srcv + row * 256 + l16 * 16;
    #pragma unroll
    for (int e = 0; e < 16; ++e) { v[e] = sp[e]; s += v[e]; q += v[e] * v[e]; }
  } else {
    const unsigned short* sp = (const unsigned short*)srcv + row * 256 + l16 * 16;
    #pragma unroll
    for (int e = 0; e < 16; ++e) { v[e] = bf2f(sp[e]); s += v[e]; q += v[e] * v[e]; }
  }
  s += __shfl_xor(s, 1); q += __shfl_xor(q, 1);
  s += __shfl_xor(s, 2); q += __shfl_xor(q, 2);
  s += __shfl_xor(s, 4); q += __shfl_xor(q, 4);
  s += __shfl_xor(s, 8); q += __shfl_xor(q, 8);
  float mu = s * (1.f / 256.f);
  float var = q * (1.f / 256.f) - mu * mu;
  float rs = rsqrtf(fmaxf(var, 0.f) + 1e-5f);
  #pragma unroll
  for (int e = 0; e < 16; ++e) {
    int c = l16 * 16 + e;
    dst[row * 256 + c] = f2bf((v[e] - mu) * rs * gw[c] + bw[c]);
  }
}

// ---------------------------------------------------------------------------
// GEMM staging: 128x32 bf16 tile via global_load_lds(16B), XOR-swizzled k-slot.
// LDS dest = wave-uniform base + lane*16 (HW rule); swizzle on GLOBAL source.
// ---------------------------------------------------------------------------
__device__ __forceinline__ void stage_tile(const unsigned short* __restrict__ src,
                                           size_t row0, unsigned short* lds,
                                           int k0, int tid) {
  #pragma unroll
  for (int it = 0; it < 2; ++it) {
    int o = (it * 256 + tid) * 16;               // byte offset in 8KB tile
    int row = o >> 6;                            // 64B per row (32 bf16)
    int ks = ((o >> 4) & 3) ^ ((row >> 1) & 3);  // source k-chunk (involution)
    gload_lds16(src + (row0 + (size_t)row) * 256 + k0 + ks * 8, (char*)lds + o);
  }
}

__device__ __forceinline__ s16x8 frag_read(const unsigned short* lds, int row, int g) {
  return *(const s16x8*)((const char*)lds + row * 64 + (((g ^ ((row >> 1) & 3)) & 3) << 4));
}

// ---------------------------------------------------------------------------
// gemm_qkv: A[32768][256]bf16 @ Wt[n][256]^T -> qkv bf16 ld=768 with
// rope(q,k)+q-scale epilogue (verified math). grid (256, N/128).
// ---------------------------------------------------------------------------
__global__ __launch_bounds__(256) void gemm_qkv(
    const unsigned short* __restrict__ A, const unsigned short* __restrict__ Bt,
    unsigned short* __restrict__ O,
    const float* __restrict__ ropeC, const float* __restrict__ ropeS, int colOff) {
  __shared__ unsigned short lA[2][128 * 32];
  __shared__ unsigned short lB[2][128 * 32];
  __shared__ float lC[512], lS[512];
  int tid = threadIdx.x;
  int m0 = blockIdx.x * 128;
  int n0 = blockIdx.y * 128;
  lC[tid] = ropeC[tid]; lC[tid + 256] = ropeC[tid + 256];
  lS[tid] = ropeS[tid]; lS[tid + 256] = ropeS[tid + 256];

  int lane = tid & 63, wv = tid >> 6;
  int r = lane & 15, g = lane >> 4;
  f32x4 acc[2][8] = {};

  stage_tile(A, m0, lA[0], 0, tid);
  stage_tile(Bt, n0, lB[0], 0, tid);
  __syncthreads();
  for (int ks = 0; ks < 8; ++ks) {
    int cur = ks & 1;
    if (ks < 7) {
      stage_tile(A, m0, lA[cur ^ 1], (ks + 1) * 32, tid);
      stage_tile(Bt, n0, lB[cur ^ 1], (ks + 1) * 32, tid);
    }
    s16x8 af[2], bfr[8];
    #pragma unroll
    for (int mt = 0; mt < 2; ++mt) af[mt] = frag_read(lA[cur], wv * 32 + mt * 16 + r, g);
    #pragma unroll
    for (int nt = 0; nt < 8; ++nt) bfr[nt] = frag_read(lB[cur], nt * 16 + r, g);
    #pragma unroll
    for (int mt = 0; mt < 2; ++mt)
      #pragma unroll
      for (int nt = 0; nt < 8; ++nt)
        acc[mt][nt] = __builtin_amdgcn_mfma_f32_16x16x32_bf16(af[mt], bfr[nt], acc[mt][nt], 0, 0, 0);
    __syncthreads();
  }

  int wrow0 = m0 + wv * 32;
  #pragma unroll
  for (int mt = 0; mt < 2; ++mt) {
    #pragma unroll
    for (int nt = 0; nt < 8; ++nt) {
      int n_g = colOff + n0 + nt * 16 + r;       // C col = lane&15 [m89]
      int chunk = n_g >> 8;                      // 0=q 1=k 2=v (uniform per tile)
      f32x4 v = acc[mt][nt];
      int rowb = wrow0 + mt * 16 + 4 * g;        // C row = 4*(lane>>4)+reg
      if (chunk < 2) {                           // rope on q,k (verified epilogue)
        float scale = (chunk == 0) ? 0.17677669529663687f : 1.0f;
        int d = n_g & 31;
        #pragma unroll
        for (int rr = 0; rr < 4; ++rr) {
          float part = __shfl_xor(v[rr], 1);     // pair partner col n^1, same token
          int tt = 4 * g + rr;                   // token t = row & 15
          float cc = lC[tt * 32 + d], ss = lS[tt * 32 + d];
          float res = (n_g & 1) ? (v[rr] * cc + part * ss) : (v[rr] * cc - part * ss);
          v[rr] = res * scale;
        }
      }
      #pragma unroll
      for (int rr = 0; rr < 4; ++rr)
        O[(size_t)(rowb + rr) * 768 + n_g] = f2bf(v[rr]);
    }
  }
}

// ---------------------------------------------------------------------------
// gemm_out: aout bf16 @ Wo^T + residual -> dst. Residual: resB (bf16) or
// resF (f32); output: fOut (f32) or bOut (bf16). grid (256, 2).
// ---------------------------------------------------------------------------
__global__ __launch_bounds__(256) void gemm_out(
    const unsigned short* __restrict__ A, const unsigned short* __restrict__ Bt,
    const unsigned short* __restrict__ resB, const float* __restrict__ resF,
    float* __restrict__ fOut, unsigned short* __restrict__ bOut) {
  __shared__ unsigned short lA[2][128 * 32];
  __shared__ unsigned short lB[2][128 * 32];
  int tid = threadIdx.x;
  int m0 = blockIdx.x * 128;
  int n0 = blockIdx.y * 128;
  int lane = tid & 63, wv = tid >> 6;
  int r = lane & 15, g = lane >> 4;
  f32x4 acc[2][8] = {};

  stage_tile(A, m0, lA[0], 0, tid);
  stage_tile(Bt, n0, lB[0], 0, tid);
  __syncthreads();
  for (int ks = 0; ks < 8; ++ks) {
    int cur = ks & 1;
    if (ks < 7) {
      stage_tile(A, m0, lA[cur ^ 1], (ks + 1) * 32, tid);
      stage_tile(Bt, n0, lB[cur ^ 1], (ks + 1) * 32, tid);
    }
    s16x8 af[2], bfr[8];
    #pragma unroll
    for (int mt = 0; mt < 2; ++mt) af[mt] = frag_read(lA[cur], wv * 32 + mt * 16 + r, g);
    #pragma unroll
    for (int nt = 0; nt < 8; ++nt) bfr[nt] = frag_read(lB[cur], nt * 16 + r, g);
    #pragma unroll
    for (int mt = 0; mt < 2; ++mt)
      #pragma unroll
      for (int nt = 0; nt < 8; ++nt)
        acc[mt][nt] = __builtin_amdgcn_mfma_f32_16x16x32_bf16(af[mt], bfr[nt], acc[mt][nt], 0, 0, 0);
    __syncthreads();
  }

  int wrow0 = m0 + wv * 32;
  #pragma unroll
  for (int mt = 0; mt < 2; ++mt) {
    #pragma unroll
    for (int nt = 0; nt < 8; ++nt) {
      int n_g = n0 + nt * 16 + r;
      int rowb = wrow0 + mt * 16 + 4 * g;
      #pragma unroll
      for (int rr = 0; rr < 4; ++rr) {
        size_t idx = (size_t)(rowb + rr) * 256 + n_g;
        float res = resB ? bf2f(resB[idx]) : resF[idx];
        float val = acc[mt][nt][rr] + res;
        if (fOut) fOut[idx] = val;
        else      bOut[idx] = f2bf(val);
      }
    }
  }
}

// ---------------------------------------------------------------------------
// attn_seq: one block per seq (16 tokens); wave wv handles heads 2wv,2wv+1.
// Exact verified Phase-C math; q,k,v read from global qkv (ld 768).
// ---------------------------------------------------------------------------
__global__ __launch_bounds__(256) void attn_seq(
    const unsigned short* __restrict__ qkvg, const float* __restrict__ pbias,
    unsigned short* __restrict__ aout) {
  __shared__ unsigned short ps[4][2][16][18];
  int tid = threadIdx.x, lane = tid & 63, wv = tid >> 6;
  size_t r0 = (size_t)blockIdx.x * 16;
  int r = lane & 15, g = lane >> 4;

  for (int hs = 0; hs < 2; ++hs) {
    int h = wv * 2 + hs;
    s16x8 kf = *(const s16x8*)&qkvg[(r0 + r) * 768 + 256 + h * 32 + g * 8];
    s16x8 qf = *(const s16x8*)&qkvg[(r0 + r) * 768 +       h * 32 + g * 8];
    f32x4 zero = {};
    f32x4 st = __builtin_amdgcn_mfma_f32_16x16x32_bf16(kf, qf, zero, 0, 0, 0);
    // lane holds sim[query=r][key=4g+rr]
    f32x4 bb = *(const f32x4*)&pbias[h * 256 + r * 16 + 4 * g];
    float p0 = st[0] + bb[0], p1 = st[1] + bb[1];
    float p2 = st[2] + bb[2], p3 = st[3] + bb[3];
    float mx = fmaxf(fmaxf(p0, p1), fmaxf(p2, p3));
    mx = fmaxf(mx, __shfl_xor(mx, 16));
    mx = fmaxf(mx, __shfl_xor(mx, 32));
    p0 = __expf(p0 - mx); p1 = __expf(p1 - mx);
    p2 = __expf(p2 - mx); p3 = __expf(p3 - mx);
    float sm = p0 + p1 + p2 + p3;
    sm += __shfl_xor(sm, 16);
    sm += __shfl_xor(sm, 32);
    float inv = 1.0f / sm;
    ps[wv][hs][4 * g + 0][r] = f2bf(p0 * inv);
    ps[wv][hs][4 * g + 1][r] = f2bf(p1 * inv);
    ps[wv][hs][4 * g + 2][r] = f2bf(p2 * inv);
    ps[wv][hs][4 * g + 3][r] = f2bf(p3 * inv);

    // out = P @ V (keys zero-padded 16->32); same-wave ps read
    #pragma unroll
    for (int dt = 0; dt < 2; ++dt) {
      s16x8 pa, bv;
      #pragma unroll
      for (int e = 0; e < 8; ++e) {
        int j = 8 * g + e;
        int jc = (j < 16) ? j : 0;
        pa[e] = (j < 16) ? (short)ps[wv][hs][jc][r] : (short)0;
        bv[e] = (short)qkvg[(r0 + jc) * 768 + 512 + h * 32 + dt * 16 + r];
      }
      f32x4 o = __builtin_amdgcn_mfma_f32_16x16x32_bf16(pa, bv, zero, 0, 0, 0);
      #pragma unroll
      for (int rr = 0; rr < 4; ++rr)
        aout[(r0 + 4 * g + rr) * 256 + h * 32 + dt * 16 + r] = f2bf(o[rr]);
    }
  }
}

// ---------------------------------------------------------------------------
// transpose_out: rows (b,hw,t)[256] (f32 or bf16) -> [b,c,t,h,w] f32
// ---------------------------------------------------------------------------
__global__ __launch_bounds__(256) void transpose_out(
    const void* __restrict__ srcv, float* __restrict__ outp, int srcF32) {
  __shared__ float lds[32][257];
  int blk = blockIdx.x, tid = threadIdx.x;
  int b = blk >> 9, t = (blk >> 5) & 15, h = blk & 31;
  size_t seqb = ((size_t)b * 1024 + (size_t)h * 32) * 16 + t;
  if (srcF32) {
    const float* sp = (const float*)srcv;
    #pragma unroll
    for (int w2 = 0; w2 < 32; ++w2)
      lds[w2][tid] = sp[(seqb + (size_t)w2 * 16) * 256 + tid];
  } else {
    const unsigned short* sp = (const unsigned short*)srcv;
    #pragma unroll
    for (int w2 = 0; w2 < 32; ++w2)
      lds[w2][tid] = bf2f(sp[(seqb + (size_t)w2 * 16) * 256 + tid]);
  }
  __syncthreads();
  int w_ = tid & 31, cg8 = tid >> 5;
  size_t base = (size_t)b * 4194304 + (size_t)t * 1024 + (size_t)h * 32 + w_;
  #pragma unroll
  for (int itr = 0; itr < 32; ++itr) {
    int c = itr * 8 + cg8;
    outp[base + (size_t)c * 16384] = lds[w_][c];
  }
}

// ---------------------------------------------------------------------------
// Fallback fused kernel (round-8 verified, unchanged).
// ---------------------------------------------------------------------------
__global__ __launch_bounds__(256) void fused_stage(
    const float* __restrict__ srcQ, const float* __restrict__ srcK,
    float* __restrict__ dst,
    const float* __restrict__ gq, const float* __restrict__ bq,
    const float* __restrict__ gk, const float* __restrict__ bk,
    const unsigned short* __restrict__ Wqkv, const unsigned short* __restrict__ Wo,
    const float* __restrict__ ropeC, const float* __restrict__ ropeS,
    const float* __restrict__ pbias, int cross) {
  __shared__ unsigned short xnQ[16 * 272];
  __shared__ unsigned short xnK[16 * 272];
  __shared__ unsigned short qkv[16 * 776];
  __shared__ unsigned short ps[4][2][16][18];

  int tid = threadIdx.x, lane = tid & 63, wv = tid >> 6;
  size_t r0 = (size_t)blockIdx.x * 16;
  int r = lane & 15, g = lane >> 4;

  {
    int row = tid >> 4, l16 = tid & 15;
    const float* sp = srcQ + (r0 + row) * 256 + l16 * 16;
    f32x4 v0 = *(const f32x4*)(sp);
    f32x4 v1 = *(const f32x4*)(sp + 4);
    f32x4 v2 = *(const f32x4*)(sp + 8);
    f32x4 v3 = *(const f32x4*)(sp + 12);
    float s = 0.f, q = 0.f;
    #pragma unroll
    for (int e = 0; e < 4; ++e) {
      s += v0[e] + v1[e] + v2[e] + v3[e];
      q += v0[e]*v0[e] + v1[e]*v1[e] + v2[e]*v2[e] + v3[e]*v3[e];
    }
    s += __shfl_xor(s, 1); q += __shfl_xor(q, 1);
    s += __shfl_xor(s, 2); q += __shfl_xor(q, 2);
    s += __shfl_xor(s, 4); q += __shfl_xor(q, 4);
    s += __shfl_xor(s, 8); q += __shfl_xor(q, 8);
    float mu = s * (1.f / 256.f);
    float var = q * (1.f / 256.f) - mu * mu;
    float rs = rsqrtf(fmaxf(var, 0.f) + 1e-5f);
    #pragma unroll
    for (int e = 0; e < 16; ++e) {
      int c = l16 * 16 + e;
      float v = (e < 4) ? v0[e] : (e < 8) ? v1[e - 4] : (e < 12) ? v2[e - 8] : v3[e - 12];
      xnQ[row * 272 + c] = f2bf((v - mu) * rs * gq[c] + bq[c]);
    }
    if (cross) {
      const float* kp = srcK + (r0 + row) * 256 + l16 * 16;
      f32x4 k0 = *(const f32x4*)(kp);
      f32x4 k1 = *(const f32x4*)(kp + 4);
      f32x4 k2 = *(const f32x4*)(kp + 8);
      f32x4 k3 = *(const f32x4*)(kp + 12);
      float sk = 0.f, qk = 0.f;
      #pragma unroll
      for (int e = 0; e < 4; ++e) {
        sk += k0[e] + k1[e] + k2[e] + k3[e];
        qk += k0[e]*k0[e] + k1[e]*k1[e] + k2[e]*k2[e] + k3[e]*k3[e];
      }
      sk += __shfl_xor(sk, 1); qk += __shfl_xor(qk, 1);
      sk += __shfl_xor(sk, 2); qk += __shfl_xor(qk, 2);
      sk += __shfl_xor(sk, 4); qk += __shfl_xor(qk, 4);
      sk += __shfl_xor(sk, 8); qk += __shfl_xor(qk, 8);
      float muk = sk * (1.f / 256.f);
      float vark = qk * (1.f / 256.f) - muk * muk;
      float rsk = rsqrtf(fmaxf(vark, 0.f) + 1e-5f);
      #pragma unroll
      for (int e = 0; e < 16; ++e) {
        int c = l16 * 16 + e;
        float v = (e < 4) ? k0[e] : (e < 8) ? k1[e - 4] : (e < 12) ? k2[e - 8] : k3[e - 12];
        xnK[row * 272 + c] = f2bf((v - muk) * rsk * gk[c] + bk[c]);
      }
    }
  }
  __syncthreads();

  const unsigned short* xnKp = cross ? xnK : xnQ;

  #pragma unroll 2
  for (int it = 0; it < 12; ++it) {
    int n0 = (wv * 12 + it) * 16;
    const unsigned short* xs = (n0 < 256) ? xnQ : xnKp;
    f32x4 acc0 = {}, acc1 = {};
    #pragma unroll
    for (int kc = 0; kc < 4; ++kc) {
      s16x8 af0 = *(const s16x8*)&xs[r * 272 + kc * 32 + g * 8];
      s16x8 bf0 = *(const s16x8*)&Wqkv[(size_t)(n0 + r) * 256 + kc * 32 + g * 8];
      acc0 = __builtin_amdgcn_mfma_f32_16x16x32_bf16(af0, bf0, acc0, 0, 0, 0);
      s16x8 af1 = *(const s16x8*)&xs[r * 272 + (kc + 4) * 32 + g * 8];
      s16x8 bf1 = *(const s16x8*)&Wqkv[(size_t)(n0 + r) * 256 + (kc + 4) * 32 + g * 8];
      acc1 = __builtin_amdgcn_mfma_f32_16x16x32_bf16(af1, bf1, acc1, 0, 0, 0);
    }
    f32x4 acc = acc0 + acc1;
    int n = n0 + r;
    if (n0 < 512) {
      float scale = (n0 < 256) ? 0.17677669529663687f : 1.0f;
      int d = n & 31;
      #pragma unroll
      for (int rr = 0; rr < 4; ++rr) {
        float part = __shfl_xor(acc[rr], 1);
        int tok = 4 * g + rr;
        float cc = ropeC[tok * 32 + d], ss = ropeS[tok * 32 + d];
        float val = (n & 1) ? (acc[rr] * cc + part * ss)
                            : (acc[rr] * cc - part * ss);
        qkv[tok * 776 + n] = f2bf(val * scale);
      }
    } else {
      #pragma unroll
      for (int rr = 0; rr < 4; ++rr)
        qkv[(4 * g + rr) * 776 + n] = f2bf(acc[rr]);
    }
  }
  __syncthreads();

  unsigned short* aout = xnQ;
  for (int hs = 0; hs < 2; ++hs) {
    int h = wv * 2 + hs;
    s16x8 kf = *(const s16x8*)&qkv[r * 776 + 256 + h * 32 + g * 8];
    s16x8 qf = *(const s16x8*)&qkv[r * 776 +       h * 32 + g * 8];
    f32x4 zero = {};
    f32x4 st = __builtin_amdgcn_mfma_f32_16x16x32_bf16(kf, qf, zero, 0, 0, 0);
    f32x4 bb = *(const f32x4*)&pbias[h * 256 + r * 16 + 4 * g];
    float p0 = st[0] + bb[0], p1 = st[1] + bb[1];
    float p2 = st[2] + bb[2], p3 = st[3] + bb[3];
    float mx = fmaxf(fmaxf(p0, p1), fmaxf(p2, p3));
    mx = fmaxf(mx, __shfl_xor(mx, 16));
    mx = fmaxf(mx, __shfl_xor(mx, 32));
    p0 = __expf(p0 - mx); p1 = __expf(p1 - mx);
    p2 = __expf(p2 - mx); p3 = __expf(p3 - mx);
    float sm = p0 + p1 + p2 + p3;
    sm += __shfl_xor(sm, 16);
    sm += __shfl_xor(sm, 32);
    float inv = 1.0f / sm;
    ps[wv][hs][4 * g + 0][r] = f2bf(p0 * inv);
    ps[wv][hs][4 * g + 1][r] = f2bf(p1 * inv);
    ps[wv][hs][4 * g + 2][r] = f2bf(p2 * inv);
    ps[wv][hs][4 * g + 3][r] = f2bf(p3 * inv);

    #pragma unroll
    for (int dt = 0; dt < 2; ++dt) {
      s16x8 pa, bv;
      #pragma unroll
      for (int e = 0; e < 8; ++e) {
        int j = 8 * g + e;
        int jc = (j < 16) ? j : 0;
        pa[e] = (j < 16) ? (short)ps[wv][hs][jc][r] : (short)0;
        bv[e] = (short)qkv[jc * 776 + 512 + h * 32 + dt * 16 + r];
      }
      f32x4 o = __builtin_amdgcn_mfma_f32_16x16x32_bf16(pa, bv, zero, 0, 0, 0);
      #pragma unroll
      for (int rr = 0; rr < 4; ++rr)
        aout[(4 * g + rr) * 272 + h * 32 + dt * 16 + r] = f2bf(o[rr]);
    }
  }
  __syncthreads();

  #pragma unroll 2
  for (int it = 0; it < 4; ++it) {
    int n0 = (wv * 4 + it) * 16;
    f32x4 acc0 = {}, acc1 = {};
    #pragma unroll
    for (int kc = 0; kc < 4; ++kc) {
      s16x8 af0 = *(const s16x8*)&aout[r * 272 + kc * 32 + g * 8];
      s16x8 bf0 = *(const s16x8*)&Wo[(size_t)(n0 + r) * 256 + kc * 32 + g * 8];
      acc0 = __builtin_amdgcn_mfma_f32_16x16x32_bf16(af0, bf0, acc0, 0, 0, 0);
      s16x8 af1 = *(const s16x8*)&aout[r * 272 + (kc + 4) * 32 + g * 8];
      s16x8 bf1 = *(const s16x8*)&Wo[(size_t)(n0 + r) * 256 + (kc + 4) * 32 + g * 8];
      acc1 = __builtin_amdgcn_mfma_f32_16x16x32_bf16(af1, bf1, acc1, 0, 0, 0);
    }
    f32x4 acc = acc0 + acc1;
    #pragma unroll
    for (int rr = 0; rr < 4; ++rr) {
      int tok = 4 * g + rr, n = n0 + r;
      size_t idx = (r0 + tok) * 256 + n;
      dst[idx] = acc[rr] + srcQ[idx];
    }
  }
}

// ---------------------------------------------------------------------------
extern "C" void kernel_launch(void* const* d_in, const int* in_sizes, int n_in,
                              void* d_out, int out_size, void* d_ws, size_t ws_size,
                              hipStream_t stream) {
  const float* x   = (const float*)d_in[0];
  const float* mm  = (const float*)d_in[1];
  const float* pb  = (const float*)d_in[2];
  const float* g1  = (const float*)d_in[3];
  const float* b1  = (const float*)d_in[4];
  const float* Wq1 = (const float*)d_in[5];
  const float* Wk1 = (const float*)d_in[6];
  const float* Wv1 = (const float*)d_in[7];
  const float* Wo1 = (const float*)d_in[8];
  const float* g2  = (const float*)d_in[9];
  const float* b2  = (const float*)d_in[10];
  const float* cg  = (const float*)d_in[11];
  const float* cb  = (const float*)d_in[12];
  const float* Wq2 = (const float*)d_in[13];
  const float* Wk2 = (const float*)d_in[14];
  const float* Wv2 = (const float*)d_in[15];
  const float* Wo2 = (const float*)d_in[16];

  char* ws = (char*)d_ws;
  unsigned short* W1t  = (unsigned short*)(ws + 0);
  unsigned short* Wo1t = (unsigned short*)(ws + 393216);
  unsigned short* W2t  = (unsigned short*)(ws + 524288);
  unsigned short* Wo2t = (unsigned short*)(ws + 917504);
  float* ropeC         = (float*)(ws + 1048576);
  float* ropeS         = (float*)(ws + 1050624);

  prep_w<<<2049, 256, 0, stream>>>(Wq1, Wk1, Wv1, Wo1, Wq2, Wk2, Wv2, Wo2,
                                   W1t, Wo1t, W2t, Wo2t, ropeC, ropeS);

  if (ws_size >= 118493184u) {
    // -------- GEMM pipeline (weight-efficient). Layout (118.5 MB): --------
    //   xt_bf  @ 1052672   bf16 raw x rows -> later stage-2 output rows
    //   mmt_bf @ 17829888  bf16 raw mm rows
    //   xnA    @ 34607104  bf16 LN rows (xn1 -> aout1 -> xn2 -> aout2)
    //   xnB    @ 51384320  bf16 LN(mm) rows (ctx)
    //   qkv    @ 68161536  bf16 [32768][768]
    // d_out holds xs1 (f32 rows) between stages.
    unsigned short* xt_bf  = (unsigned short*)(ws + 1052672);
    unsigned short* mmt_bf = (unsigned short*)(ws + 17829888);
    unsigned short* xnA    = (unsigned short*)(ws + 34607104);
    unsigned short* xnB    = (unsigned short*)(ws + 51384320);
    unsigned short* qkv    = (unsigned short*)(ws + 68161536);
    unsigned short* aout   = xnA;        // aliases: xnA dead when aout live
    unsigned short* rows2  = xt_bf;      // xt dead after gemm_out1
    float* xs1             = (float*)d_out;
    float* outp            = (float*)d_out;

    transpose_in<<<2048, 256, 0, stream>>>(x, mm, xt_bf, mmt_bf, 1);
    ln_rows<<<2048, 256, 0, stream>>>(xt_bf, g1, b1, xnA, 0);
    ln_rows<<<2048, 256, 0, stream>>>(mmt_bf, cg, cb, xnB, 0);
    // stage 1
    gemm_qkv<<<dim3(256, 6), 256, 0, stream>>>(xnA, W1t, qkv, ropeC, ropeS, 0);
    attn_seq<<<2048, 256, 0, stream>>>(qkv, pb, aout);
    gemm_out<<<dim3(256, 2), 256, 0, stream>>>(aout, Wo1t, xt_bf, nullptr, xs1, nullptr);
    // stage 2
    ln_rows<<<2048, 256, 0, stream>>>(xs1, g2, b2, xnA, 1);
    gemm_qkv<<<dim3(256, 2), 256, 0, stream>>>(xnA, W2t, qkv, ropeC, ropeS, 0);
    gemm_qkv<<<dim3(256, 4), 256, 0, stream>>>(xnB, W2t + 65536, qkv, ropeC, ropeS, 256);
    attn_seq<<<2048, 256, 0, stream>>>(qkv, pb, aout);
    gemm_out<<<dim3(256, 2), 256, 0, stream>>>(aout, Wo2t, nullptr, xs1, nullptr, rows2);
    transpose_out<<<1024, 256, 0, stream>>>(rows2, outp, 0);
  } else {
    // -------- Fallback: round-8 passing fused pipeline (68.2 MB) --------
    float* xt  = (float*)(ws + 1052672);
    float* mmt = (float*)(ws + 34607104);
    float* xs1 = (float*)d_out;
    float* outp = (float*)d_out;

    transpose_in<<<2048, 256, 0, stream>>>(x, mm, xt, mmt, 0);
    fused_stage<<<2048, 256, 0, stream>>>(xt, xt, xs1, g1, b1, g1, b1,
                                          W1t, Wo1t, ropeC, ropeS, pb, 0);
    fused_stage<<<2048, 256, 0, stream>>>(xs1, mmt, xt, g2, b2, cg, cb,
                                          W2t, Wo2t, ropeC, ropeS, pb, 1);
    transpose_out<<<1024, 256, 0, stream>>>(xt, outp, 1);
  }
}

// Round 10
// 195.902 us; speedup vs baseline: 1.5985x; 1.1140x over previous
//
#include <hip/hip_runtime.h>

typedef __attribute__((ext_vector_type(4))) float f32x4;
typedef __attribute__((ext_vector_type(8))) short s16x8;

__device__ __forceinline__ unsigned short f2bf(float f) {
  union { float f; unsigned int i; } x; x.f = f;
  unsigned int lsb = (x.i >> 16) & 1u;
  x.i += 0x7fffu + lsb;            // round-to-nearest-even
  return (unsigned short)(x.i >> 16);
}

__device__ __forceinline__ float bf2f(unsigned short u) {
  union { unsigned int i; float f; } x;
  x.i = ((unsigned int)u) << 16;
  return x.f;
}

__device__ __forceinline__ void gload_lds16(const void* gsrc, void* ldst) {
  __builtin_amdgcn_global_load_lds(
      (const __attribute__((address_space(1))) void*)gsrc,
      (__attribute__((address_space(3))) void*)ldst, 16, 0, 0);
}

// ---------------------------------------------------------------------------
// prep_w: W^T (n-major) bf16 weights + rope tables (all inputs f32).
// ---------------------------------------------------------------------------
__global__ void prep_w(const float* __restrict__ Wq1, const float* __restrict__ Wk1,
                       const float* __restrict__ Wv1, const float* __restrict__ Wo1,
                       const float* __restrict__ Wq2, const float* __restrict__ Wk2,
                       const float* __restrict__ Wv2, const float* __restrict__ Wo2,
                       unsigned short* __restrict__ W1t, unsigned short* __restrict__ Wo1t,
                       unsigned short* __restrict__ W2t, unsigned short* __restrict__ Wo2t,
                       float* __restrict__ ropeC, float* __restrict__ ropeS) {
  int blk = blockIdx.x, tid = threadIdx.x;
  if (blk < 768) {
    int n = blk, k = tid;
    const float* src = (n < 256) ? Wq1 : (n < 512 ? Wk1 : Wv1);
    W1t[n * 256 + k] = f2bf(src[k * 256 + (n & 255)]);
  } else if (blk < 1024) {
    int n = blk - 768, k = tid;
    Wo1t[n * 256 + k] = f2bf(Wo1[k * 256 + n]);
  } else if (blk < 1792) {
    int n = blk - 1024, k = tid;
    const float* src = (n < 256) ? Wq2 : (n < 512 ? Wk2 : Wv2);
    W2t[n * 256 + k] = f2bf(src[k * 256 + (n & 255)]);
  } else if (blk < 2048) {
    int n = blk - 1792, k = tid;
    Wo2t[n * 256 + k] = f2bf(Wo2[k * 256 + n]);
  } else {
    #pragma unroll
    for (int it = 0; it < 2; ++it) {
      int idx = it * 256 + tid;          // 512 entries: t(16) x d(32)
      int t = idx >> 5, d = idx & 31;
      float inv = exp2f(-13.287712379549449f * (float)(d & 30) * (1.0f / 32.0f));
      float ang = (float)t * inv;
      ropeC[idx] = cosf(ang);
      ropeS[idx] = sinf(ang);
    }
  }
}

// ---------------------------------------------------------------------------
// transpose_ln: [b,c,t,h,w] f32 -> rows (b, h*32+w, t) of [256], fused LN.
// blocks 0..1023 (x):  write raw bf16 rows -> xt_raw, LN rows -> xnA
// blocks 1024..2047 (mm): write LN rows -> xnB only
// LN reduction = verified ln_rows pattern (16 lanes/row, shfl_xor 1/2/4/8).
// ---------------------------------------------------------------------------
__global__ __launch_bounds__(256) void transpose_ln(
    const float* __restrict__ X, const float* __restrict__ MM,
    const float* __restrict__ g1w, const float* __restrict__ b1w,
    const float* __restrict__ cgw, const float* __restrict__ cbw,
    unsigned short* __restrict__ xt_raw, unsigned short* __restrict__ xnA,
    unsigned short* __restrict__ xnB) {
  __shared__ float lds[32][257];
  int blk = blockIdx.x, tid = threadIdx.x;
  bool isX = blk < 1024;
  int idx = blk & 1023;
  int b = idx >> 9, t = (idx >> 5) & 15, h = idx & 31;
  const float* src = isX ? X : MM;
  const float* gw  = isX ? g1w : cgw;
  const float* bw  = isX ? b1w : cbw;

  int w_ = tid & 31, cg8 = tid >> 5;
  size_t base = (size_t)b * 4194304 + (size_t)t * 1024 + (size_t)h * 32 + w_;
  #pragma unroll
  for (int itr = 0; itr < 32; ++itr) {
    int c = itr * 8 + cg8;
    lds[w_][c] = src[base + (size_t)c * 16384];
  }
  __syncthreads();

  size_t seqb = ((size_t)b * 1024 + (size_t)h * 32) * 16 + t;
  if (isX) {   // raw residual rows
    #pragma unroll
    for (int w2 = 0; w2 < 32; ++w2)
      xt_raw[(seqb + (size_t)w2 * 16) * 256 + tid] = f2bf(lds[w2][tid]);
  }

  unsigned short* dst = isX ? xnA : xnB;
  int l16 = tid & 15;
  #pragma unroll
  for (int rr2 = 0; rr2 < 2; ++rr2) {
    int w = rr2 * 16 + (tid >> 4);     // row within block (16 rows per pass)
    float v[16], s = 0.f, q = 0.f;
    #pragma unroll
    for (int e = 0; e < 16; ++e) {
      v[e] = lds[w][l16 * 16 + e];
      s += v[e]; q += v[e] * v[e];
    }
    s += __shfl_xor(s, 1); q += __shfl_xor(q, 1);
    s += __shfl_xor(s, 2); q += __shfl_xor(q, 2);
    s += __shfl_xor(s, 4); q += __shfl_xor(q, 4);
    s += __shfl_xor(s, 8); q += __shfl_xor(q, 8);
    float mu = s * (1.f / 256.f);
    float var = q * (1.f / 256.f) - mu * mu;
    float rs = rsqrtf(fmaxf(var, 0.f) + 1e-5f);
    size_t orow = (seqb + (size_t)w * 16) * 256;
    #pragma unroll
    for (int e = 0; e < 16; ++e) {
      int c = l16 * 16 + e;
      dst[orow + c] = f2bf((v[e] - mu) * rs * gw[c] + bw[c]);
    }
  }
}

// ---------------------------------------------------------------------------
// transpose_in (fallback path): [b,c,t,h,w] f32 -> f32 rows.
// ---------------------------------------------------------------------------
__global__ __launch_bounds__(256) void transpose_in(
    const float* __restrict__ X, const float* __restrict__ MM,
    float* __restrict__ xtv, float* __restrict__ mmtv) {
  __shared__ float lds[32][257];
  int blk = blockIdx.x, tid = threadIdx.x;
  bool isX = blk < 1024;
  int idx = blk & 1023;
  int b = idx >> 9, t = (idx >> 5) & 15, h = idx & 31;
  const float* src = isX ? X : MM;
  float* dstp = isX ? xtv : mmtv;

  int w_ = tid & 31, cg8 = tid >> 5;
  size_t base = (size_t)b * 4194304 + (size_t)t * 1024 + (size_t)h * 32 + w_;
  #pragma unroll
  for (int itr = 0; itr < 32; ++itr) {
    int c = itr * 8 + cg8;
    lds[w_][c] = src[base + (size_t)c * 16384];
  }
  __syncthreads();
  size_t seqb = ((size_t)b * 1024 + (size_t)h * 32) * 16 + t;
  #pragma unroll
  for (int w2 = 0; w2 < 32; ++w2)
    dstp[(seqb + (size_t)w2 * 16) * 256 + tid] = lds[w2][tid];
}

// ---------------------------------------------------------------------------
// ln_rows: rowwise LayerNorm over 256; src f32 rows -> bf16 rows.
// ---------------------------------------------------------------------------
__global__ __launch_bounds__(256) void ln_rows(
    const float* __restrict__ srcv, const float* __restrict__ gw,
    const float* __restrict__ bw, unsigned short* __restrict__ dst) {
  int tid = threadIdx.x;
  size_t row = (size_t)blockIdx.x * 16 + (tid >> 4);
  int l16 = tid & 15;
  const float* sp = srcv + row * 256 + l16 * 16;
  float v[16], s = 0.f, q = 0.f;
  #pragma unroll
  for (int e = 0; e < 16; ++e) { v[e] = sp[e]; s += v[e]; q += v[e] * v[e]; }
  s += __shfl_xor(s, 1); q += __shfl_xor(q, 1);
  s += __shfl_xor(s, 2); q += __shfl_xor(q, 2);
  s += __shfl_xor(s, 4); q += __shfl_xor(q, 4);
  s += __shfl_xor(s, 8); q += __shfl_xor(q, 8);
  float mu = s * (1.f / 256.f);
  float var = q * (1.f / 256.f) - mu * mu;
  float rs = rsqrtf(fmaxf(var, 0.f) + 1e-5f);
  #pragma unroll
  for (int e = 0; e < 16; ++e) {
    int c = l16 * 16 + e;
    dst[row * 256 + c] = f2bf((v[e] - mu) * rs * gw[c] + bw[c]);
  }
}

// ---------------------------------------------------------------------------
// GEMM staging: 128x32 bf16 tile via global_load_lds(16B), XOR-swizzled k-slot.
// ---------------------------------------------------------------------------
__device__ __forceinline__ void stage_tile(const unsigned short* __restrict__ src,
                                           size_t row0, unsigned short* lds,
                                           int k0, int tid) {
  #pragma unroll
  for (int it = 0; it < 2; ++it) {
    int o = (it * 256 + tid) * 16;               // byte offset in 8KB tile
    int row = o >> 6;                            // 64B per row (32 bf16)
    int ks = ((o >> 4) & 3) ^ ((row >> 1) & 3);  // source k-chunk (involution)
    gload_lds16(src + (row0 + (size_t)row) * 256 + k0 + ks * 8, (char*)lds + o);
  }
}

__device__ __forceinline__ s16x8 frag_read(const unsigned short* lds, int row, int g) {
  return *(const s16x8*)((const char*)lds + row * 64 + (((g ^ ((row >> 1) & 3)) & 3) << 4));
}

// ---------------------------------------------------------------------------
// gemm_qkv: A[32768][256]bf16 @ Wt[768][256]^T -> qkv bf16 ld=768 with
// rope(q,k)+q-scale epilogue. grid (256, 6). A source selected per n-block:
// n0<256 -> Aq (query rows), else Akv (key/value rows).
// ---------------------------------------------------------------------------
__global__ __launch_bounds__(256) void gemm_qkv(
    const unsigned short* __restrict__ Aq, const unsigned short* __restrict__ Akv,
    const unsigned short* __restrict__ Bt, unsigned short* __restrict__ O,
    const float* __restrict__ ropeC, const float* __restrict__ ropeS) {
  __shared__ unsigned short lA[2][128 * 32];
  __shared__ unsigned short lB[2][128 * 32];
  __shared__ float lC[512], lS[512];
  int tid = threadIdx.x;
  int m0 = blockIdx.x * 128;
  int n0 = blockIdx.y * 128;
  const unsigned short* A = (n0 < 256) ? Aq : Akv;
  lC[tid] = ropeC[tid]; lC[tid + 256] = ropeC[tid + 256];
  lS[tid] = ropeS[tid]; lS[tid + 256] = ropeS[tid + 256];

  int lane = tid & 63, wv = tid >> 6;
  int r = lane & 15, g = lane >> 4;
  f32x4 acc[2][8] = {};

  stage_tile(A, m0, lA[0], 0, tid);
  stage_tile(Bt, n0, lB[0], 0, tid);
  __syncthreads();
  for (int ks = 0; ks < 8; ++ks) {
    int cur = ks & 1;
    if (ks < 7) {
      stage_tile(A, m0, lA[cur ^ 1], (ks + 1) * 32, tid);
      stage_tile(Bt, n0, lB[cur ^ 1], (ks + 1) * 32, tid);
    }
    s16x8 af[2], bfr[8];
    #pragma unroll
    for (int mt = 0; mt < 2; ++mt) af[mt] = frag_read(lA[cur], wv * 32 + mt * 16 + r, g);
    #pragma unroll
    for (int nt = 0; nt < 8; ++nt) bfr[nt] = frag_read(lB[cur], nt * 16 + r, g);
    #pragma unroll
    for (int mt = 0; mt < 2; ++mt)
      #pragma unroll
      for (int nt = 0; nt < 8; ++nt)
        acc[mt][nt] = __builtin_amdgcn_mfma_f32_16x16x32_bf16(af[mt], bfr[nt], acc[mt][nt], 0, 0, 0);
    __syncthreads();
  }

  int wrow0 = m0 + wv * 32;
  #pragma unroll
  for (int mt = 0; mt < 2; ++mt) {
    #pragma unroll
    for (int nt = 0; nt < 8; ++nt) {
      int n_g = n0 + nt * 16 + r;                // C col = lane&15 [m89]
      int chunk = n_g >> 8;                      // 0=q 1=k 2=v (uniform per block)
      f32x4 v = acc[mt][nt];
      int rowb = wrow0 + mt * 16 + 4 * g;        // C row = 4*(lane>>4)+reg
      if (chunk < 2) {                           // rope on q,k (verified epilogue)
        float scale = (chunk == 0) ? 0.17677669529663687f : 1.0f;
        int d = n_g & 31;
        #pragma unroll
        for (int rr = 0; rr < 4; ++rr) {
          float part = __shfl_xor(v[rr], 1);     // pair partner col n^1, same token
          int tt = 4 * g + rr;                   // token t = row & 15
          float cc = lC[tt * 32 + d], ss = lS[tt * 32 + d];
          float res = (n_g & 1) ? (v[rr] * cc + part * ss) : (v[rr] * cc - part * ss);
          v[rr] = res * scale;
        }
      }
      #pragma unroll
      for (int rr = 0; rr < 4; ++rr)
        O[(size_t)(rowb + rr) * 768 + n_g] = f2bf(v[rr]);
    }
  }
}

// ---------------------------------------------------------------------------
// gemm_out: aout bf16 @ Wo^T + residual -> dst. Residual: resB (bf16) or
// resF (f32); output: fOut (f32) or bOut (bf16). grid (256, 2).
// ---------------------------------------------------------------------------
__global__ __launch_bounds__(256) void gemm_out(
    const unsigned short* __restrict__ A, const unsigned short* __restrict__ Bt,
    const unsigned short* __restrict__ resB, const float* __restrict__ resF,
    float* __restrict__ fOut, unsigned short* __restrict__ bOut) {
  __shared__ unsigned short lA[2][128 * 32];
  __shared__ unsigned short lB[2][128 * 32];
  int tid = threadIdx.x;
  int m0 = blockIdx.x * 128;
  int n0 = blockIdx.y * 128;
  int lane = tid & 63, wv = tid >> 6;
  int r = lane & 15, g = lane >> 4;
  f32x4 acc[2][8] = {};

  stage_tile(A, m0, lA[0], 0, tid);
  stage_tile(Bt, n0, lB[0], 0, tid);
  __syncthreads();
  for (int ks = 0; ks < 8; ++ks) {
    int cur = ks & 1;
    if (ks < 7) {
      stage_tile(A, m0, lA[cur ^ 1], (ks + 1) * 32, tid);
      stage_tile(Bt, n0, lB[cur ^ 1], (ks + 1) * 32, tid);
    }
    s16x8 af[2], bfr[8];
    #pragma unroll
    for (int mt = 0; mt < 2; ++mt) af[mt] = frag_read(lA[cur], wv * 32 + mt * 16 + r, g);
    #pragma unroll
    for (int nt = 0; nt < 8; ++nt) bfr[nt] = frag_read(lB[cur], nt * 16 + r, g);
    #pragma unroll
    for (int mt = 0; mt < 2; ++mt)
      #pragma unroll
      for (int nt = 0; nt < 8; ++nt)
        acc[mt][nt] = __builtin_amdgcn_mfma_f32_16x16x32_bf16(af[mt], bfr[nt], acc[mt][nt], 0, 0, 0);
    __syncthreads();
  }

  int wrow0 = m0 + wv * 32;
  #pragma unroll
  for (int mt = 0; mt < 2; ++mt) {
    #pragma unroll
    for (int nt = 0; nt < 8; ++nt) {
      int n_g = n0 + nt * 16 + r;
      int rowb = wrow0 + mt * 16 + 4 * g;
      #pragma unroll
      for (int rr = 0; rr < 4; ++rr) {
        size_t idx = (size_t)(rowb + rr) * 256 + n_g;
        float res = resB ? bf2f(resB[idx]) : resF[idx];
        float val = acc[mt][nt][rr] + res;
        if (fOut) fOut[idx] = val;
        else      bOut[idx] = f2bf(val);
      }
    }
  }
}

// ---------------------------------------------------------------------------
// attn_seq: one block per seq (16 tokens); wave wv handles heads 2wv,2wv+1.
// ---------------------------------------------------------------------------
__global__ __launch_bounds__(256) void attn_seq(
    const unsigned short* __restrict__ qkvg, const float* __restrict__ pbias,
    unsigned short* __restrict__ aout) {
  __shared__ unsigned short ps[4][2][16][18];
  int tid = threadIdx.x, lane = tid & 63, wv = tid >> 6;
  size_t r0 = (size_t)blockIdx.x * 16;
  int r = lane & 15, g = lane >> 4;

  for (int hs = 0; hs < 2; ++hs) {
    int h = wv * 2 + hs;
    s16x8 kf = *(const s16x8*)&qkvg[(r0 + r) * 768 + 256 + h * 32 + g * 8];
    s16x8 qf = *(const s16x8*)&qkvg[(r0 + r) * 768 +       h * 32 + g * 8];
    f32x4 zero = {};
    f32x4 st = __builtin_amdgcn_mfma_f32_16x16x32_bf16(kf, qf, zero, 0, 0, 0);
    // lane holds sim[query=r][key=4g+rr]
    f32x4 bb = *(const f32x4*)&pbias[h * 256 + r * 16 + 4 * g];
    float p0 = st[0] + bb[0], p1 = st[1] + bb[1];
    float p2 = st[2] + bb[2], p3 = st[3] + bb[3];
    float mx = fmaxf(fmaxf(p0, p1), fmaxf(p2, p3));
    mx = fmaxf(mx, __shfl_xor(mx, 16));
    mx = fmaxf(mx, __shfl_xor(mx, 32));
    p0 = __expf(p0 - mx); p1 = __expf(p1 - mx);
    p2 = __expf(p2 - mx); p3 = __expf(p3 - mx);
    float sm = p0 + p1 + p2 + p3;
    sm += __shfl_xor(sm, 16);
    sm += __shfl_xor(sm, 32);
    float inv = 1.0f / sm;
    ps[wv][hs][4 * g + 0][r] = f2bf(p0 * inv);
    ps[wv][hs][4 * g + 1][r] = f2bf(p1 * inv);
    ps[wv][hs][4 * g + 2][r] = f2bf(p2 * inv);
    ps[wv][hs][4 * g + 3][r] = f2bf(p3 * inv);

    // out = P @ V (keys zero-padded 16->32); same-wave ps read
    #pragma unroll
    for (int dt = 0; dt < 2; ++dt) {
      s16x8 pa, bv;
      #pragma unroll
      for (int e = 0; e < 8; ++e) {
        int j = 8 * g + e;
        int jc = (j < 16) ? j : 0;
        pa[e] = (j < 16) ? (short)ps[wv][hs][jc][r] : (short)0;
        bv[e] = (short)qkvg[(r0 + jc) * 768 + 512 + h * 32 + dt * 16 + r];
      }
      f32x4 o = __builtin_amdgcn_mfma_f32_16x16x32_bf16(pa, bv, zero, 0, 0, 0);
      #pragma unroll
      for (int rr = 0; rr < 4; ++rr)
        aout[(r0 + 4 * g + rr) * 256 + h * 32 + dt * 16 + r] = f2bf(o[rr]);
    }
  }
}

// ---------------------------------------------------------------------------
// transpose_out: rows (b,hw,t)[256] (f32 or bf16) -> [b,c,t,h,w] f32
// ---------------------------------------------------------------------------
__global__ __launch_bounds__(256) void transpose_out(
    const void* __restrict__ srcv, float* __restrict__ outp, int srcF32) {
  __shared__ float lds[32][257];
  int blk = blockIdx.x, tid = threadIdx.x;
  int b = blk >> 9, t = (blk >> 5) & 15, h = blk & 31;
  size_t seqb = ((size_t)b * 1024 + (size_t)h * 32) * 16 + t;
  if (srcF32) {
    const float* sp = (const float*)srcv;
    #pragma unroll
    for (int w2 = 0; w2 < 32; ++w2)
      lds[w2][tid] = sp[(seqb + (size_t)w2 * 16) * 256 + tid];
  } else {
    const unsigned short* sp = (const unsigned short*)srcv;
    #pragma unroll
    for (int w2 = 0; w2 < 32; ++w2)
      lds[w2][tid] = bf2f(sp[(seqb + (size_t)w2 * 16) * 256 + tid]);
  }
  __syncthreads();
  int w_ = tid & 31, cg8 = tid >> 5;
  size_t base = (size_t)b * 4194304 + (size_t)t * 1024 + (size_t)h * 32 + w_;
  #pragma unroll
  for (int itr = 0; itr < 32; ++itr) {
    int c = itr * 8 + cg8;
    outp[base + (size_t)c * 16384] = lds[w_][c];
  }
}

// ---------------------------------------------------------------------------
// Fallback fused kernel (round-8 verified, unchanged).
// ---------------------------------------------------------------------------
__global__ __launch_bounds__(256) void fused_stage(
    const float* __restrict__ srcQ, const float* __restrict__ srcK,
    float* __restrict__ dst,
    const float* __restrict__ gq, const float* __restrict__ bq,
    const float* __restrict__ gk, const float* __restrict__ bk,
    const unsigned short* __restrict__ Wqkv, const unsigned short* __restrict__ Wo,
    const float* __restrict__ ropeC, const float* __restrict__ ropeS,
    const float* __restrict__ pbias, int cross) {
  __shared__ unsigned short xnQ[16 * 272];
  __shared__ unsigned short xnK[16 * 272];
  __shared__ unsigned short qkv[16 * 776];
  __shared__ unsigned short ps[4][2][16][18];

  int tid = threadIdx.x, lane = tid & 63, wv = tid >> 6;
  size_t r0 = (size_t)blockIdx.x * 16;
  int r = lane & 15, g = lane >> 4;

  {
    int row = tid >> 4, l16 = tid & 15;
    const float* sp = srcQ + (r0 + row) * 256 + l16 * 16;
    f32x4 v0 = *(const f32x4*)(sp);
    f32x4 v1 = *(const f32x4*)(sp + 4);
    f32x4 v2 = *(const f32x4*)(sp + 8);
    f32x4 v3 = *(const f32x4*)(sp + 12);
    float s = 0.f, q = 0.f;
    #pragma unroll
    for (int e = 0; e < 4; ++e) {
      s += v0[e] + v1[e] + v2[e] + v3[e];
      q += v0[e]*v0[e] + v1[e]*v1[e] + v2[e]*v2[e] + v3[e]*v3[e];
    }
    s += __shfl_xor(s, 1); q += __shfl_xor(q, 1);
    s += __shfl_xor(s, 2); q += __shfl_xor(q, 2);
    s += __shfl_xor(s, 4); q += __shfl_xor(q, 4);
    s += __shfl_xor(s, 8); q += __shfl_xor(q, 8);
    float mu = s * (1.f / 256.f);
    float var = q * (1.f / 256.f) - mu * mu;
    float rs = rsqrtf(fmaxf(var, 0.f) + 1e-5f);
    #pragma unroll
    for (int e = 0; e < 16; ++e) {
      int c = l16 * 16 + e;
      float v = (e < 4) ? v0[e] : (e < 8) ? v1[e - 4] : (e < 12) ? v2[e - 8] : v3[e - 12];
      xnQ[row * 272 + c] = f2bf((v - mu) * rs * gq[c] + bq[c]);
    }
    if (cross) {
      const float* kp = srcK + (r0 + row) * 256 + l16 * 16;
      f32x4 k0 = *(const f32x4*)(kp);
      f32x4 k1 = *(const f32x4*)(kp + 4);
      f32x4 k2 = *(const f32x4*)(kp + 8);
      f32x4 k3 = *(const f32x4*)(kp + 12);
      float sk = 0.f, qk = 0.f;
      #pragma unroll
      for (int e = 0; e < 4; ++e) {
        sk += k0[e] + k1[e] + k2[e] + k3[e];
        qk += k0[e]*k0[e] + k1[e]*k1[e] + k2[e]*k2[e] + k3[e]*k3[e];
      }
      sk += __shfl_xor(sk, 1); qk += __shfl_xor(qk, 1);
      sk += __shfl_xor(sk, 2); qk += __shfl_xor(qk, 2);
      sk += __shfl_xor(sk, 4); qk += __shfl_xor(qk, 4);
      sk += __shfl_xor(sk, 8); qk += __shfl_xor(qk, 8);
      float muk = sk * (1.f / 256.f);
      float vark = qk * (1.f / 256.f) - muk * muk;
      float rsk = rsqrtf(fmaxf(vark, 0.f) + 1e-5f);
      #pragma unroll
      for (int e = 0; e < 16; ++e) {
        int c = l16 * 16 + e;
        float v = (e < 4) ? k0[e] : (e < 8) ? k1[e - 4] : (e < 12) ? k2[e - 8] : k3[e - 12];
        xnK[row * 272 + c] = f2bf((v - muk) * rsk * gk[c] + bk[c]);
      }
    }
  }
  __syncthreads();

  const unsigned short* xnKp = cross ? xnK : xnQ;

  #pragma unroll 2
  for (int it = 0; it < 12; ++it) {
    int n0 = (wv * 12 + it) * 16;
    const unsigned short* xs = (n0 < 256) ? xnQ : xnKp;
    f32x4 acc0 = {}, acc1 = {};
    #pragma unroll
    for (int kc = 0; kc < 4; ++kc) {
      s16x8 af0 = *(const s16x8*)&xs[r * 272 + kc * 32 + g * 8];
      s16x8 bf0 = *(const s16x8*)&Wqkv[(size_t)(n0 + r) * 256 + kc * 32 + g * 8];
      acc0 = __builtin_amdgcn_mfma_f32_16x16x32_bf16(af0, bf0, acc0, 0, 0, 0);
      s16x8 af1 = *(const s16x8*)&xs[r * 272 + (kc + 4) * 32 + g * 8];
      s16x8 bf1 = *(const s16x8*)&Wqkv[(size_t)(n0 + r) * 256 + (kc + 4) * 32 + g * 8];
      acc1 = __builtin_amdgcn_mfma_f32_16x16x32_bf16(af1, bf1, acc1, 0, 0, 0);
    }
    f32x4 acc = acc0 + acc1;
    int n = n0 + r;
    if (n0 < 512) {
      float scale = (n0 < 256) ? 0.17677669529663687f : 1.0f;
      int d = n & 31;
      #pragma unroll
      for (int rr = 0; rr < 4; ++rr) {
        float part = __shfl_xor(acc[rr], 1);
        int tok = 4 * g + rr;
        float cc = ropeC[tok * 32 + d], ss = ropeS[tok * 32 + d];
        float val = (n & 1) ? (acc[rr] * cc + part * ss)
                            : (acc[rr] * cc - part * ss);
        qkv[tok * 776 + n] = f2bf(val * scale);
      }
    } else {
      #pragma unroll
      for (int rr = 0; rr < 4; ++rr)
        qkv[(4 * g + rr) * 776 + n] = f2bf(acc[rr]);
    }
  }
  __syncthreads();

  unsigned short* aout = xnQ;
  for (int hs = 0; hs < 2; ++hs) {
    int h = wv * 2 + hs;
    s16x8 kf = *(const s16x8*)&qkv[r * 776 + 256 + h * 32 + g * 8];
    s16x8 qf = *(const s16x8*)&qkv[r * 776 +       h * 32 + g * 8];
    f32x4 zero = {};
    f32x4 st = __builtin_amdgcn_mfma_f32_16x16x32_bf16(kf, qf, zero, 0, 0, 0);
    f32x4 bb = *(const f32x4*)&pbias[h * 256 + r * 16 + 4 * g];
    float p0 = st[0] + bb[0], p1 = st[1] + bb[1];
    float p2 = st[2] + bb[2], p3 = st[3] + bb[3];
    float mx = fmaxf(fmaxf(p0, p1), fmaxf(p2, p3));
    mx = fmaxf(mx, __shfl_xor(mx, 16));
    mx = fmaxf(mx, __shfl_xor(mx, 32));
    p0 = __expf(p0 - mx); p1 = __expf(p1 - mx);
    p2 = __expf(p2 - mx); p3 = __expf(p3 - mx);
    float sm = p0 + p1 + p2 + p3;
    sm += __shfl_xor(sm, 16);
    sm += __shfl_xor(sm, 32);
    float inv = 1.0f / sm;
    ps[wv][hs][4 * g + 0][r] = f2bf(p0 * inv);
    ps[wv][hs][4 * g + 1][r] = f2bf(p1 * inv);
    ps[wv][hs][4 * g + 2][r] = f2bf(p2 * inv);
    ps[wv][hs][4 * g + 3][r] = f2bf(p3 * inv);

    #pragma unroll
    for (int dt = 0; dt < 2; ++dt) {
      s16x8 pa, bv;
      #pragma unroll
      for (int e = 0; e < 8; ++e) {
        int j = 8 * g + e;
        int jc = (j < 16) ? j : 0;
        pa[e] = (j < 16) ? (short)ps[wv][hs][jc][r] : (short)0;
        bv[e] = (short)qkv[jc * 776 + 512 + h * 32 + dt * 16 + r];
      }
      f32x4 o = __builtin_amdgcn_mfma_f32_16x16x32_bf16(pa, bv, zero, 0, 0, 0);
      #pragma unroll
      for (int rr = 0; rr < 4; ++rr)
        aout[(4 * g + rr) * 272 + h * 32 + dt * 16 + r] = f2bf(o[rr]);
    }
  }
  __syncthreads();

  #pragma unroll 2
  for (int it = 0; it < 4; ++it) {
    int n0 = (wv * 4 + it) * 16;
    f32x4 acc0 = {}, acc1 = {};
    #pragma unroll
    for (int kc = 0; kc < 4; ++kc) {
      s16x8 af0 = *(const s16x8*)&aout[r * 272 + kc * 32 + g * 8];
      s16x8 bf0 = *(const s16x8*)&Wo[(size_t)(n0 + r) * 256 + kc * 32 + g * 8];
      acc0 = __builtin_amdgcn_mfma_f32_16x16x32_bf16(af0, bf0, acc0, 0, 0, 0);
      s16x8 af1 = *(const s16x8*)&aout[r * 272 + (kc + 4) * 32 + g * 8];
      s16x8 bf1 = *(const s16x8*)&Wo[(size_t)(n0 + r) * 256 + (kc + 4) * 32 + g * 8];
      acc1 = __builtin_amdgcn_mfma_f32_16x16x32_bf16(af1, bf1, acc1, 0, 0, 0);
    }
    f32x4 acc = acc0 + acc1;
    #pragma unroll
    for (int rr = 0; rr < 4; ++rr) {
      int tok = 4 * g + rr, n = n0 + r;
      size_t idx = (r0 + tok) * 256 + n;
      dst[idx] = acc[rr] + srcQ[idx];
    }
  }
}

// ---------------------------------------------------------------------------
extern "C" void kernel_launch(void* const* d_in, const int* in_sizes, int n_in,
                              void* d_out, int out_size, void* d_ws, size_t ws_size,
                              hipStream_t stream) {
  const float* x   = (const float*)d_in[0];
  const float* mm  = (const float*)d_in[1];
  const float* pb  = (const float*)d_in[2];
  const float* g1  = (const float*)d_in[3];
  const float* b1  = (const float*)d_in[4];
  const float* Wq1 = (const float*)d_in[5];
  const float* Wk1 = (const float*)d_in[6];
  const float* Wv1 = (const float*)d_in[7];
  const float* Wo1 = (const float*)d_in[8];
  const float* g2  = (const float*)d_in[9];
  const float* b2  = (const float*)d_in[10];
  const float* cg  = (const float*)d_in[11];
  const float* cb  = (const float*)d_in[12];
  const float* Wq2 = (const float*)d_in[13];
  const float* Wk2 = (const float*)d_in[14];
  const float* Wv2 = (const float*)d_in[15];
  const float* Wo2 = (const float*)d_in[16];

  char* ws = (char*)d_ws;
  unsigned short* W1t  = (unsigned short*)(ws + 0);
  unsigned short* Wo1t = (unsigned short*)(ws + 393216);
  unsigned short* W2t  = (unsigned short*)(ws + 524288);
  unsigned short* Wo2t = (unsigned short*)(ws + 917504);
  float* ropeC         = (float*)(ws + 1048576);
  float* ropeS         = (float*)(ws + 1050624);

  prep_w<<<2049, 256, 0, stream>>>(Wq1, Wk1, Wv1, Wo1, Wq2, Wk2, Wv2, Wo2,
                                   W1t, Wo1t, W2t, Wo2t, ropeC, ropeS);

  if (ws_size >= 118493184u) {
    // -------- GEMM pipeline. Layout (118.5 MB): --------
    //   xt_bf  @ 1052672   bf16 raw x rows -> later stage-2 output rows
    //   xnA    @ 34607104  bf16 LN rows (xn1 -> aout1 -> xn2 -> aout2)
    //   xnB    @ 51384320  bf16 LN(mm) rows (ctx)
    //   qkv    @ 68161536  bf16 [32768][768]
    // d_out holds xs1 (f32 rows) between stages.
    unsigned short* xt_bf  = (unsigned short*)(ws + 1052672);
    unsigned short* xnA    = (unsigned short*)(ws + 34607104);
    unsigned short* xnB    = (unsigned short*)(ws + 51384320);
    unsigned short* qkv    = (unsigned short*)(ws + 68161536);
    unsigned short* aout   = xnA;        // alias: xnA dead when aout live
    unsigned short* rows2  = xt_bf;      // xt raw dead after gemm_out#1
    float* xs1             = (float*)d_out;
    float* outp            = (float*)d_out;

    transpose_ln<<<2048, 256, 0, stream>>>(x, mm, g1, b1, cg, cb, xt_bf, xnA, xnB);
    // stage 1: q,k,v all from xn1
    gemm_qkv<<<dim3(256, 6), 256, 0, stream>>>(xnA, xnA, W1t, qkv, ropeC, ropeS);
    attn_seq<<<2048, 256, 0, stream>>>(qkv, pb, aout);
    gemm_out<<<dim3(256, 2), 256, 0, stream>>>(aout, Wo1t, xt_bf, nullptr, xs1, nullptr);
    // stage 2: q from LN(xs1), k/v from ctx
    ln_rows<<<2048, 256, 0, stream>>>(xs1, g2, b2, xnA);
    gemm_qkv<<<dim3(256, 6), 256, 0, stream>>>(xnA, xnB, W2t, qkv, ropeC, ropeS);
    attn_seq<<<2048, 256, 0, stream>>>(qkv, pb, aout);
    gemm_out<<<dim3(256, 2), 256, 0, stream>>>(aout, Wo2t, nullptr, xs1, nullptr, rows2);
    transpose_out<<<1024, 256, 0, stream>>>(rows2, outp, 0);
  } else {
    // -------- Fallback: round-8 verified fused pipeline (68.2 MB) --------
    float* xt  = (float*)(ws + 1052672);
    float* mmt = (float*)(ws + 34607104);
    float* xs1 = (float*)d_out;
    float* outp = (float*)d_out;

    transpose_in<<<2048, 256, 0, stream>>>(x, mm, xt, mmt);
    fused_stage<<<2048, 256, 0, stream>>>(xt, xt, xs1, g1, b1, g1, b1,
                                          W1t, Wo1t, ropeC, ropeS, pb, 0);
    fused_stage<<<2048, 256, 0, stream>>>(xs1, mmt, xt, g2, b2, cg, cb,
                                          W2t, Wo2t, ropeC, ropeS, pb, 1);
    transpose_out<<<1024, 256, 0, stream>>>(xt, outp, 1);
  }
}

// Round 11
// 186.631 us; speedup vs baseline: 1.6779x; 1.0497x over previous
//
#include <hip/hip_runtime.h>

typedef __attribute__((ext_vector_type(4))) float f32x4;
typedef __attribute__((ext_vector_type(8))) short s16x8;

__device__ __forceinline__ unsigned short f2bf(float f) {
  union { float f; unsigned int i; } x; x.f = f;
  unsigned int lsb = (x.i >> 16) & 1u;
  x.i += 0x7fffu + lsb;            // round-to-nearest-even
  return (unsigned short)(x.i >> 16);
}

__device__ __forceinline__ float bf2f(unsigned short u) {
  union { unsigned int i; float f; } x;
  x.i = ((unsigned int)u) << 16;
  return x.f;
}

__device__ __forceinline__ void gload_lds16(const void* gsrc, void* ldst) {
  __builtin_amdgcn_global_load_lds(
      (const __attribute__((address_space(1))) void*)gsrc,
      (__attribute__((address_space(3))) void*)ldst, 16, 0, 0);
}

// ---------------------------------------------------------------------------
// prep_all: blocks 0..2047 = transpose+LN of x/mm; 2048..4095 = weight
// transpose to bf16 W^T; 4096 = rope tables. (Bodies identical to the
// verified prep_w / transpose_ln kernels; merged to save a launch.)
// ---------------------------------------------------------------------------
__global__ __launch_bounds__(256) void prep_all(
    const float* __restrict__ X, const float* __restrict__ MM,
    const float* __restrict__ g1w, const float* __restrict__ b1w,
    const float* __restrict__ cgw, const float* __restrict__ cbw,
    unsigned short* __restrict__ xt_raw, unsigned short* __restrict__ xnA,
    unsigned short* __restrict__ xnB,
    const float* __restrict__ Wq1, const float* __restrict__ Wk1,
    const float* __restrict__ Wv1, const float* __restrict__ Wo1,
    const float* __restrict__ Wq2, const float* __restrict__ Wk2,
    const float* __restrict__ Wv2, const float* __restrict__ Wo2,
    unsigned short* __restrict__ W1t, unsigned short* __restrict__ Wo1t,
    unsigned short* __restrict__ W2t, unsigned short* __restrict__ Wo2t,
    float* __restrict__ ropeC, float* __restrict__ ropeS) {
  __shared__ float lds[32][257];
  int blk0 = blockIdx.x, tid = threadIdx.x;

  if (blk0 >= 2048) {            // ---- weight prep (prep_w body) ----
    int blk = blk0 - 2048;
    if (blk < 768) {
      int n = blk, k = tid;
      const float* src = (n < 256) ? Wq1 : (n < 512 ? Wk1 : Wv1);
      W1t[n * 256 + k] = f2bf(src[k * 256 + (n & 255)]);
    } else if (blk < 1024) {
      int n = blk - 768, k = tid;
      Wo1t[n * 256 + k] = f2bf(Wo1[k * 256 + n]);
    } else if (blk < 1792) {
      int n = blk - 1024, k = tid;
      const float* src = (n < 256) ? Wq2 : (n < 512 ? Wk2 : Wv2);
      W2t[n * 256 + k] = f2bf(src[k * 256 + (n & 255)]);
    } else if (blk < 2048) {
      int n = blk - 1792, k = tid;
      Wo2t[n * 256 + k] = f2bf(Wo2[k * 256 + n]);
    } else {
      #pragma unroll
      for (int it = 0; it < 2; ++it) {
        int idx = it * 256 + tid;        // 512 entries: t(16) x d(32)
        int t = idx >> 5, d = idx & 31;
        float inv = exp2f(-13.287712379549449f * (float)(d & 30) * (1.0f / 32.0f));
        float ang = (float)t * inv;
        ropeC[idx] = cosf(ang);
        ropeS[idx] = sinf(ang);
      }
    }
    return;
  }

  // ---- transpose + LN (transpose_ln body) ----
  bool isX = blk0 < 1024;
  int idx = blk0 & 1023;
  int b = idx >> 9, t = (idx >> 5) & 15, h = idx & 31;
  const float* src = isX ? X : MM;
  const float* gw  = isX ? g1w : cgw;
  const float* bw  = isX ? b1w : cbw;

  int w_ = tid & 31, cg8 = tid >> 5;
  size_t base = (size_t)b * 4194304 + (size_t)t * 1024 + (size_t)h * 32 + w_;
  #pragma unroll
  for (int itr = 0; itr < 32; ++itr) {
    int c = itr * 8 + cg8;
    lds[w_][c] = src[base + (size_t)c * 16384];
  }
  __syncthreads();

  size_t seqb = ((size_t)b * 1024 + (size_t)h * 32) * 16 + t;
  if (isX) {   // raw residual rows
    #pragma unroll
    for (int w2 = 0; w2 < 32; ++w2)
      xt_raw[(seqb + (size_t)w2 * 16) * 256 + tid] = f2bf(lds[w2][tid]);
  }

  unsigned short* dst = isX ? xnA : xnB;
  int l16 = tid & 15;
  #pragma unroll
  for (int rr2 = 0; rr2 < 2; ++rr2) {
    int w = rr2 * 16 + (tid >> 4);     // row within block (16 rows per pass)
    float v[16], s = 0.f, q = 0.f;
    #pragma unroll
    for (int e = 0; e < 16; ++e) {
      v[e] = lds[w][l16 * 16 + e];
      s += v[e]; q += v[e] * v[e];
    }
    s += __shfl_xor(s, 1); q += __shfl_xor(q, 1);
    s += __shfl_xor(s, 2); q += __shfl_xor(q, 2);
    s += __shfl_xor(s, 4); q += __shfl_xor(q, 4);
    s += __shfl_xor(s, 8); q += __shfl_xor(q, 8);
    float mu = s * (1.f / 256.f);
    float var = q * (1.f / 256.f) - mu * mu;
    float rs = rsqrtf(fmaxf(var, 0.f) + 1e-5f);
    size_t orow = (seqb + (size_t)w * 16) * 256;
    #pragma unroll
    for (int e = 0; e < 16; ++e) {
      int c = l16 * 16 + e;
      dst[orow + c] = f2bf((v[e] - mu) * rs * gw[c] + bw[c]);
    }
  }
}

// ---------------------------------------------------------------------------
// prep_w (fallback path only)
// ---------------------------------------------------------------------------
__global__ void prep_w(const float* __restrict__ Wq1, const float* __restrict__ Wk1,
                       const float* __restrict__ Wv1, const float* __restrict__ Wo1,
                       const float* __restrict__ Wq2, const float* __restrict__ Wk2,
                       const float* __restrict__ Wv2, const float* __restrict__ Wo2,
                       unsigned short* __restrict__ W1t, unsigned short* __restrict__ Wo1t,
                       unsigned short* __restrict__ W2t, unsigned short* __restrict__ Wo2t,
                       float* __restrict__ ropeC, float* __restrict__ ropeS) {
  int blk = blockIdx.x, tid = threadIdx.x;
  if (blk < 768) {
    int n = blk, k = tid;
    const float* src = (n < 256) ? Wq1 : (n < 512 ? Wk1 : Wv1);
    W1t[n * 256 + k] = f2bf(src[k * 256 + (n & 255)]);
  } else if (blk < 1024) {
    int n = blk - 768, k = tid;
    Wo1t[n * 256 + k] = f2bf(Wo1[k * 256 + n]);
  } else if (blk < 1792) {
    int n = blk - 1024, k = tid;
    const float* src = (n < 256) ? Wq2 : (n < 512 ? Wk2 : Wv2);
    W2t[n * 256 + k] = f2bf(src[k * 256 + (n & 255)]);
  } else if (blk < 2048) {
    int n = blk - 1792, k = tid;
    Wo2t[n * 256 + k] = f2bf(Wo2[k * 256 + n]);
  } else {
    #pragma unroll
    for (int it = 0; it < 2; ++it) {
      int idx = it * 256 + tid;
      int t = idx >> 5, d = idx & 31;
      float inv = exp2f(-13.287712379549449f * (float)(d & 30) * (1.0f / 32.0f));
      float ang = (float)t * inv;
      ropeC[idx] = cosf(ang);
      ropeS[idx] = sinf(ang);
    }
  }
}

// ---------------------------------------------------------------------------
// transpose_in (fallback path): [b,c,t,h,w] f32 -> f32 rows.
// ---------------------------------------------------------------------------
__global__ __launch_bounds__(256) void transpose_in(
    const float* __restrict__ X, const float* __restrict__ MM,
    float* __restrict__ xtv, float* __restrict__ mmtv) {
  __shared__ float lds[32][257];
  int blk = blockIdx.x, tid = threadIdx.x;
  bool isX = blk < 1024;
  int idx = blk & 1023;
  int b = idx >> 9, t = (idx >> 5) & 15, h = idx & 31;
  const float* src = isX ? X : MM;
  float* dstp = isX ? xtv : mmtv;

  int w_ = tid & 31, cg8 = tid >> 5;
  size_t base = (size_t)b * 4194304 + (size_t)t * 1024 + (size_t)h * 32 + w_;
  #pragma unroll
  for (int itr = 0; itr < 32; ++itr) {
    int c = itr * 8 + cg8;
    lds[w_][c] = src[base + (size_t)c * 16384];
  }
  __syncthreads();
  size_t seqb = ((size_t)b * 1024 + (size_t)h * 32) * 16 + t;
  #pragma unroll
  for (int w2 = 0; w2 < 32; ++w2)
    dstp[(seqb + (size_t)w2 * 16) * 256 + tid] = lds[w2][tid];
}

// ---------------------------------------------------------------------------
// ln_rows: rowwise LayerNorm over 256; f32 rows -> bf16 rows. grid 512,
// 64 rows/block (4 x 16-row groups).
// ---------------------------------------------------------------------------
__global__ __launch_bounds__(256) void ln_rows(
    const float* __restrict__ srcv, const float* __restrict__ gw,
    const float* __restrict__ bw, unsigned short* __restrict__ dst) {
  int tid = threadIdx.x;
  int l16 = tid & 15;
  #pragma unroll
  for (int it = 0; it < 4; ++it) {
    size_t row = (size_t)blockIdx.x * 64 + it * 16 + (tid >> 4);
    const float* sp = srcv + row * 256 + l16 * 16;
    float v[16], s = 0.f, q = 0.f;
    #pragma unroll
    for (int e = 0; e < 16; ++e) { v[e] = sp[e]; s += v[e]; q += v[e] * v[e]; }
    s += __shfl_xor(s, 1); q += __shfl_xor(q, 1);
    s += __shfl_xor(s, 2); q += __shfl_xor(q, 2);
    s += __shfl_xor(s, 4); q += __shfl_xor(q, 4);
    s += __shfl_xor(s, 8); q += __shfl_xor(q, 8);
    float mu = s * (1.f / 256.f);
    float var = q * (1.f / 256.f) - mu * mu;
    float rs = rsqrtf(fmaxf(var, 0.f) + 1e-5f);
    #pragma unroll
    for (int e = 0; e < 16; ++e) {
      int c = l16 * 16 + e;
      dst[row * 256 + c] = f2bf((v[e] - mu) * rs * gw[c] + bw[c]);
    }
  }
}

// ---------------------------------------------------------------------------
// GEMM staging: 128x32 bf16 tile via global_load_lds(16B), XOR-swizzled k-slot.
// ---------------------------------------------------------------------------
__device__ __forceinline__ void stage_tile(const unsigned short* __restrict__ src,
                                           size_t row0, unsigned short* lds,
                                           int k0, int tid) {
  #pragma unroll
  for (int it = 0; it < 2; ++it) {
    int o = (it * 256 + tid) * 16;               // byte offset in 8KB tile
    int row = o >> 6;                            // 64B per row (32 bf16)
    int ks = ((o >> 4) & 3) ^ ((row >> 1) & 3);  // source k-chunk (involution)
    gload_lds16(src + (row0 + (size_t)row) * 256 + k0 + ks * 8, (char*)lds + o);
  }
}

__device__ __forceinline__ s16x8 frag_read(const unsigned short* lds, int row, int g) {
  return *(const s16x8*)((const char*)lds + row * 64 + (((g ^ ((row >> 1) & 3)) & 3) << 4));
}

// ---------------------------------------------------------------------------
// gemm_qkv: A[32768][256]bf16 @ Wt[768][256]^T -> qkv bf16 ld=768 with
// rope(q,k)+q-scale epilogue. grid (256, 6). A per n-block: n0<256 -> Aq,
// else Akv.
// ---------------------------------------------------------------------------
__global__ __launch_bounds__(256) void gemm_qkv(
    const unsigned short* __restrict__ Aq, const unsigned short* __restrict__ Akv,
    const unsigned short* __restrict__ Bt, unsigned short* __restrict__ O,
    const float* __restrict__ ropeC, const float* __restrict__ ropeS) {
  __shared__ unsigned short lA[2][128 * 32];
  __shared__ unsigned short lB[2][128 * 32];
  __shared__ float lC[512], lS[512];
  int tid = threadIdx.x;
  int m0 = blockIdx.x * 128;
  int n0 = blockIdx.y * 128;
  const unsigned short* A = (n0 < 256) ? Aq : Akv;
  lC[tid] = ropeC[tid]; lC[tid + 256] = ropeC[tid + 256];
  lS[tid] = ropeS[tid]; lS[tid + 256] = ropeS[tid + 256];

  int lane = tid & 63, wv = tid >> 6;
  int r = lane & 15, g = lane >> 4;
  f32x4 acc[2][8] = {};

  stage_tile(A, m0, lA[0], 0, tid);
  stage_tile(Bt, n0, lB[0], 0, tid);
  __syncthreads();
  for (int ks = 0; ks < 8; ++ks) {
    int cur = ks & 1;
    if (ks < 7) {
      stage_tile(A, m0, lA[cur ^ 1], (ks + 1) * 32, tid);
      stage_tile(Bt, n0, lB[cur ^ 1], (ks + 1) * 32, tid);
    }
    s16x8 af[2], bfr[8];
    #pragma unroll
    for (int mt = 0; mt < 2; ++mt) af[mt] = frag_read(lA[cur], wv * 32 + mt * 16 + r, g);
    #pragma unroll
    for (int nt = 0; nt < 8; ++nt) bfr[nt] = frag_read(lB[cur], nt * 16 + r, g);
    #pragma unroll
    for (int mt = 0; mt < 2; ++mt)
      #pragma unroll
      for (int nt = 0; nt < 8; ++nt)
        acc[mt][nt] = __builtin_amdgcn_mfma_f32_16x16x32_bf16(af[mt], bfr[nt], acc[mt][nt], 0, 0, 0);
    __syncthreads();
  }

  int wrow0 = m0 + wv * 32;
  #pragma unroll
  for (int mt = 0; mt < 2; ++mt) {
    #pragma unroll
    for (int nt = 0; nt < 8; ++nt) {
      int n_g = n0 + nt * 16 + r;                // C col = lane&15 [m89]
      int chunk = n_g >> 8;                      // 0=q 1=k 2=v (uniform per block)
      f32x4 v = acc[mt][nt];
      int rowb = wrow0 + mt * 16 + 4 * g;        // C row = 4*(lane>>4)+reg
      if (chunk < 2) {                           // rope on q,k (verified epilogue)
        float scale = (chunk == 0) ? 0.17677669529663687f : 1.0f;
        int d = n_g & 31;
        #pragma unroll
        for (int rr = 0; rr < 4; ++rr) {
          float part = __shfl_xor(v[rr], 1);     // pair partner col n^1, same token
          int tt = 4 * g + rr;                   // token t = row & 15
          float cc = lC[tt * 32 + d], ss = lS[tt * 32 + d];
          float res = (n_g & 1) ? (v[rr] * cc + part * ss) : (v[rr] * cc - part * ss);
          v[rr] = res * scale;
        }
      }
      #pragma unroll
      for (int rr = 0; rr < 4; ++rr)
        O[(size_t)(rowb + rr) * 768 + n_g] = f2bf(v[rr]);
    }
  }
}

// ---------------------------------------------------------------------------
// gemm_out: aout bf16 @ Wo^T + residual -> dst. grid (256, 2).
// ---------------------------------------------------------------------------
__global__ __launch_bounds__(256) void gemm_out(
    const unsigned short* __restrict__ A, const unsigned short* __restrict__ Bt,
    const unsigned short* __restrict__ resB, const float* __restrict__ resF,
    float* __restrict__ fOut, unsigned short* __restrict__ bOut) {
  __shared__ unsigned short lA[2][128 * 32];
  __shared__ unsigned short lB[2][128 * 32];
  int tid = threadIdx.x;
  int m0 = blockIdx.x * 128;
  int n0 = blockIdx.y * 128;
  int lane = tid & 63, wv = tid >> 6;
  int r = lane & 15, g = lane >> 4;
  f32x4 acc[2][8] = {};

  stage_tile(A, m0, lA[0], 0, tid);
  stage_tile(Bt, n0, lB[0], 0, tid);
  __syncthreads();
  for (int ks = 0; ks < 8; ++ks) {
    int cur = ks & 1;
    if (ks < 7) {
      stage_tile(A, m0, lA[cur ^ 1], (ks + 1) * 32, tid);
      stage_tile(Bt, n0, lB[cur ^ 1], (ks + 1) * 32, tid);
    }
    s16x8 af[2], bfr[8];
    #pragma unroll
    for (int mt = 0; mt < 2; ++mt) af[mt] = frag_read(lA[cur], wv * 32 + mt * 16 + r, g);
    #pragma unroll
    for (int nt = 0; nt < 8; ++nt) bfr[nt] = frag_read(lB[cur], nt * 16 + r, g);
    #pragma unroll
    for (int mt = 0; mt < 2; ++mt)
      #pragma unroll
      for (int nt = 0; nt < 8; ++nt)
        acc[mt][nt] = __builtin_amdgcn_mfma_f32_16x16x32_bf16(af[mt], bfr[nt], acc[mt][nt], 0, 0, 0);
    __syncthreads();
  }

  int wrow0 = m0 + wv * 32;
  #pragma unroll
  for (int mt = 0; mt < 2; ++mt) {
    #pragma unroll
    for (int nt = 0; nt < 8; ++nt) {
      int n_g = n0 + nt * 16 + r;
      int rowb = wrow0 + mt * 16 + 4 * g;
      #pragma unroll
      for (int rr = 0; rr < 4; ++rr) {
        size_t idx = (size_t)(rowb + rr) * 256 + n_g;
        float res = resB ? bf2f(resB[idx]) : resF[idx];
        float val = acc[mt][nt][rr] + res;
        if (fOut) fOut[idx] = val;
        else      bOut[idx] = f2bf(val);
      }
    }
  }
}

// ---------------------------------------------------------------------------
// attn_seq: grid 512; each block handles 4 seqs; wave wv = heads 2wv,2wv+1.
// Body per (seq,head) identical to verified version.
// ---------------------------------------------------------------------------
__global__ __launch_bounds__(256) void attn_seq(
    const unsigned short* __restrict__ qkvg, const float* __restrict__ pbias,
    unsigned short* __restrict__ aout) {
  __shared__ unsigned short ps[4][2][16][18];
  int tid = threadIdx.x, lane = tid & 63, wv = tid >> 6;
  int r = lane & 15, g = lane >> 4;

  for (int s4 = 0; s4 < 4; ++s4) {
    size_t r0 = ((size_t)blockIdx.x * 4 + s4) * 16;
    for (int hs = 0; hs < 2; ++hs) {
      int h = wv * 2 + hs;
      s16x8 kf = *(const s16x8*)&qkvg[(r0 + r) * 768 + 256 + h * 32 + g * 8];
      s16x8 qf = *(const s16x8*)&qkvg[(r0 + r) * 768 +       h * 32 + g * 8];
      f32x4 zero = {};
      f32x4 st = __builtin_amdgcn_mfma_f32_16x16x32_bf16(kf, qf, zero, 0, 0, 0);
      // lane holds sim[query=r][key=4g+rr]
      f32x4 bb = *(const f32x4*)&pbias[h * 256 + r * 16 + 4 * g];
      float p0 = st[0] + bb[0], p1 = st[1] + bb[1];
      float p2 = st[2] + bb[2], p3 = st[3] + bb[3];
      float mx = fmaxf(fmaxf(p0, p1), fmaxf(p2, p3));
      mx = fmaxf(mx, __shfl_xor(mx, 16));
      mx = fmaxf(mx, __shfl_xor(mx, 32));
      p0 = __expf(p0 - mx); p1 = __expf(p1 - mx);
      p2 = __expf(p2 - mx); p3 = __expf(p3 - mx);
      float sm = p0 + p1 + p2 + p3;
      sm += __shfl_xor(sm, 16);
      sm += __shfl_xor(sm, 32);
      float inv = 1.0f / sm;
      ps[wv][hs][4 * g + 0][r] = f2bf(p0 * inv);
      ps[wv][hs][4 * g + 1][r] = f2bf(p1 * inv);
      ps[wv][hs][4 * g + 2][r] = f2bf(p2 * inv);
      ps[wv][hs][4 * g + 3][r] = f2bf(p3 * inv);

      // out = P @ V (keys zero-padded 16->32); same-wave ps read
      #pragma unroll
      for (int dt = 0; dt < 2; ++dt) {
        s16x8 pa, bv;
        #pragma unroll
        for (int e = 0; e < 8; ++e) {
          int j = 8 * g + e;
          int jc = (j < 16) ? j : 0;
          pa[e] = (j < 16) ? (short)ps[wv][hs][jc][r] : (short)0;
          bv[e] = (short)qkvg[(r0 + jc) * 768 + 512 + h * 32 + dt * 16 + r];
        }
        f32x4 o = __builtin_amdgcn_mfma_f32_16x16x32_bf16(pa, bv, zero, 0, 0, 0);
        #pragma unroll
        for (int rr = 0; rr < 4; ++rr)
          aout[(r0 + 4 * g + rr) * 256 + h * 32 + dt * 16 + r] = f2bf(o[rr]);
      }
    }
  }
}

// ---------------------------------------------------------------------------
// transpose_out: rows (b,hw,t)[256] (f32 or bf16) -> [b,c,t,h,w] f32
// ---------------------------------------------------------------------------
__global__ __launch_bounds__(256) void transpose_out(
    const void* __restrict__ srcv, float* __restrict__ outp, int srcF32) {
  __shared__ float lds[32][257];
  int blk = blockIdx.x, tid = threadIdx.x;
  int b = blk >> 9, t = (blk >> 5) & 15, h = blk & 31;
  size_t seqb = ((size_t)b * 1024 + (size_t)h * 32) * 16 + t;
  if (srcF32) {
    const float* sp = (const float*)srcv;
    #pragma unroll
    for (int w2 = 0; w2 < 32; ++w2)
      lds[w2][tid] = sp[(seqb + (size_t)w2 * 16) * 256 + tid];
  } else {
    const unsigned short* sp = (const unsigned short*)srcv;
    #pragma unroll
    for (int w2 = 0; w2 < 32; ++w2)
      lds[w2][tid] = bf2f(sp[(seqb + (size_t)w2 * 16) * 256 + tid]);
  }
  __syncthreads();
  int w_ = tid & 31, cg8 = tid >> 5;
  size_t base = (size_t)b * 4194304 + (size_t)t * 1024 + (size_t)h * 32 + w_;
  #pragma unroll
  for (int itr = 0; itr < 32; ++itr) {
    int c = itr * 8 + cg8;
    outp[base + (size_t)c * 16384] = lds[w_][c];
  }
}

// ---------------------------------------------------------------------------
// Fallback fused kernel (round-8 verified, unchanged).
// ---------------------------------------------------------------------------
__global__ __launch_bounds__(256) void fused_stage(
    const float* __restrict__ srcQ, const float* __restrict__ srcK,
    float* __restrict__ dst,
    const float* __restrict__ gq, const float* __restrict__ bq,
    const float* __restrict__ gk, const float* __restrict__ bk,
    const unsigned short* __restrict__ Wqkv, const unsigned short* __restrict__ Wo,
    const float* __restrict__ ropeC, const float* __restrict__ ropeS,
    const float* __restrict__ pbias, int cross) {
  __shared__ unsigned short xnQ[16 * 272];
  __shared__ unsigned short xnK[16 * 272];
  __shared__ unsigned short qkv[16 * 776];
  __shared__ unsigned short ps[4][2][16][18];

  int tid = threadIdx.x, lane = tid & 63, wv = tid >> 6;
  size_t r0 = (size_t)blockIdx.x * 16;
  int r = lane & 15, g = lane >> 4;

  {
    int row = tid >> 4, l16 = tid & 15;
    const float* sp = srcQ + (r0 + row) * 256 + l16 * 16;
    f32x4 v0 = *(const f32x4*)(sp);
    f32x4 v1 = *(const f32x4*)(sp + 4);
    f32x4 v2 = *(const f32x4*)(sp + 8);
    f32x4 v3 = *(const f32x4*)(sp + 12);
    float s = 0.f, q = 0.f;
    #pragma unroll
    for (int e = 0; e < 4; ++e) {
      s += v0[e] + v1[e] + v2[e] + v3[e];
      q += v0[e]*v0[e] + v1[e]*v1[e] + v2[e]*v2[e] + v3[e]*v3[e];
    }
    s += __shfl_xor(s, 1); q += __shfl_xor(q, 1);
    s += __shfl_xor(s, 2); q += __shfl_xor(q, 2);
    s += __shfl_xor(s, 4); q += __shfl_xor(q, 4);
    s += __shfl_xor(s, 8); q += __shfl_xor(q, 8);
    float mu = s * (1.f / 256.f);
    float var = q * (1.f / 256.f) - mu * mu;
    float rs = rsqrtf(fmaxf(var, 0.f) + 1e-5f);
    #pragma unroll
    for (int e = 0; e < 16; ++e) {
      int c = l16 * 16 + e;
      float v = (e < 4) ? v0[e] : (e < 8) ? v1[e - 4] : (e < 12) ? v2[e - 8] : v3[e - 12];
      xnQ[row * 272 + c] = f2bf((v - mu) * rs * gq[c] + bq[c]);
    }
    if (cross) {
      const float* kp = srcK + (r0 + row) * 256 + l16 * 16;
      f32x4 k0 = *(const f32x4*)(kp);
      f32x4 k1 = *(const f32x4*)(kp + 4);
      f32x4 k2 = *(const f32x4*)(kp + 8);
      f32x4 k3 = *(const f32x4*)(kp + 12);
      float sk = 0.f, qk = 0.f;
      #pragma unroll
      for (int e = 0; e < 4; ++e) {
        sk += k0[e] + k1[e] + k2[e] + k3[e];
        qk += k0[e]*k0[e] + k1[e]*k1[e] + k2[e]*k2[e] + k3[e]*k3[e];
      }
      sk += __shfl_xor(sk, 1); qk += __shfl_xor(qk, 1);
      sk += __shfl_xor(sk, 2); qk += __shfl_xor(qk, 2);
      sk += __shfl_xor(sk, 4); qk += __shfl_xor(qk, 4);
      sk += __shfl_xor(sk, 8); qk += __shfl_xor(qk, 8);
      float muk = sk * (1.f / 256.f);
      float vark = qk * (1.f / 256.f) - muk * muk;
      float rsk = rsqrtf(fmaxf(vark, 0.f) + 1e-5f);
      #pragma unroll
      for (int e = 0; e < 16; ++e) {
        int c = l16 * 16 + e;
        float v = (e < 4) ? k0[e] : (e < 8) ? k1[e - 4] : (e < 12) ? k2[e - 8] : k3[e - 12];
        xnK[row * 272 + c] = f2bf((v - muk) * rsk * gk[c] + bk[c]);
      }
    }
  }
  __syncthreads();

  const unsigned short* xnKp = cross ? xnK : xnQ;

  #pragma unroll 2
  for (int it = 0; it < 12; ++it) {
    int n0 = (wv * 12 + it) * 16;
    const unsigned short* xs = (n0 < 256) ? xnQ : xnKp;
    f32x4 acc0 = {}, acc1 = {};
    #pragma unroll
    for (int kc = 0; kc < 4; ++kc) {
      s16x8 af0 = *(const s16x8*)&xs[r * 272 + kc * 32 + g * 8];
      s16x8 bf0 = *(const s16x8*)&Wqkv[(size_t)(n0 + r) * 256 + kc * 32 + g * 8];
      acc0 = __builtin_amdgcn_mfma_f32_16x16x32_bf16(af0, bf0, acc0, 0, 0, 0);
      s16x8 af1 = *(const s16x8*)&xs[r * 272 + (kc + 4) * 32 + g * 8];
      s16x8 bf1 = *(const s16x8*)&Wqkv[(size_t)(n0 + r) * 256 + (kc + 4) * 32 + g * 8];
      acc1 = __builtin_amdgcn_mfma_f32_16x16x32_bf16(af1, bf1, acc1, 0, 0, 0);
    }
    f32x4 acc = acc0 + acc1;
    int n = n0 + r;
    if (n0 < 512) {
      float scale = (n0 < 256) ? 0.17677669529663687f : 1.0f;
      int d = n & 31;
      #pragma unroll
      for (int rr = 0; rr < 4; ++rr) {
        float part = __shfl_xor(acc[rr], 1);
        int tok = 4 * g + rr;
        float cc = ropeC[tok * 32 + d], ss = ropeS[tok * 32 + d];
        float val = (n & 1) ? (acc[rr] * cc + part * ss)
                            : (acc[rr] * cc - part * ss);
        qkv[tok * 776 + n] = f2bf(val * scale);
      }
    } else {
      #pragma unroll
      for (int rr = 0; rr < 4; ++rr)
        qkv[(4 * g + rr) * 776 + n] = f2bf(acc[rr]);
    }
  }
  __syncthreads();

  unsigned short* aout = xnQ;
  for (int hs = 0; hs < 2; ++hs) {
    int h = wv * 2 + hs;
    s16x8 kf = *(const s16x8*)&qkv[r * 776 + 256 + h * 32 + g * 8];
    s16x8 qf = *(const s16x8*)&qkv[r * 776 +       h * 32 + g * 8];
    f32x4 zero = {};
    f32x4 st = __builtin_amdgcn_mfma_f32_16x16x32_bf16(kf, qf, zero, 0, 0, 0);
    f32x4 bb = *(const f32x4*)&pbias[h * 256 + r * 16 + 4 * g];
    float p0 = st[0] + bb[0], p1 = st[1] + bb[1];
    float p2 = st[2] + bb[2], p3 = st[3] + bb[3];
    float mx = fmaxf(fmaxf(p0, p1), fmaxf(p2, p3));
    mx = fmaxf(mx, __shfl_xor(mx, 16));
    mx = fmaxf(mx, __shfl_xor(mx, 32));
    p0 = __expf(p0 - mx); p1 = __expf(p1 - mx);
    p2 = __expf(p2 - mx); p3 = __expf(p3 - mx);
    float sm = p0 + p1 + p2 + p3;
    sm += __shfl_xor(sm, 16);
    sm += __shfl_xor(sm, 32);
    float inv = 1.0f / sm;
    ps[wv][hs][4 * g + 0][r] = f2bf(p0 * inv);
    ps[wv][hs][4 * g + 1][r] = f2bf(p1 * inv);
    ps[wv][hs][4 * g + 2][r] = f2bf(p2 * inv);
    ps[wv][hs][4 * g + 3][r] = f2bf(p3 * inv);

    #pragma unroll
    for (int dt = 0; dt < 2; ++dt) {
      s16x8 pa, bv;
      #pragma unroll
      for (int e = 0; e < 8; ++e) {
        int j = 8 * g + e;
        int jc = (j < 16) ? j : 0;
        pa[e] = (j < 16) ? (short)ps[wv][hs][jc][r] : (short)0;
        bv[e] = (short)qkv[jc * 776 + 512 + h * 32 + dt * 16 + r];
      }
      f32x4 o = __builtin_amdgcn_mfma_f32_16x16x32_bf16(pa, bv, zero, 0, 0, 0);
      #pragma unroll
      for (int rr = 0; rr < 4; ++rr)
        aout[(4 * g + rr) * 272 + h * 32 + dt * 16 + r] = f2bf(o[rr]);
    }
  }
  __syncthreads();

  #pragma unroll 2
  for (int it = 0; it < 4; ++it) {
    int n0 = (wv * 4 + it) * 16;
    f32x4 acc0 = {}, acc1 = {};
    #pragma unroll
    for (int kc = 0; kc < 4; ++kc) {
      s16x8 af0 = *(const s16x8*)&aout[r * 272 + kc * 32 + g * 8];
      s16x8 bf0 = *(const s16x8*)&Wo[(size_t)(n0 + r) * 256 + kc * 32 + g * 8];
      acc0 = __builtin_amdgcn_mfma_f32_16x16x32_bf16(af0, bf0, acc0, 0, 0, 0);
      s16x8 af1 = *(const s16x8*)&aout[r * 272 + (kc + 4) * 32 + g * 8];
      s16x8 bf1 = *(const s16x8*)&Wo[(size_t)(n0 + r) * 256 + (kc + 4) * 32 + g * 8];
      acc1 = __builtin_amdgcn_mfma_f32_16x16x32_bf16(af1, bf1, acc1, 0, 0, 0);
    }
    f32x4 acc = acc0 + acc1;
    #pragma unroll
    for (int rr = 0; rr < 4; ++rr) {
      int tok = 4 * g + rr, n = n0 + r;
      size_t idx = (r0 + tok) * 256 + n;
      dst[idx] = acc[rr] + srcQ[idx];
    }
  }
}

// ---------------------------------------------------------------------------
extern "C" void kernel_launch(void* const* d_in, const int* in_sizes, int n_in,
                              void* d_out, int out_size, void* d_ws, size_t ws_size,
                              hipStream_t stream) {
  const float* x   = (const float*)d_in[0];
  const float* mm  = (const float*)d_in[1];
  const float* pb  = (const float*)d_in[2];
  const float* g1  = (const float*)d_in[3];
  const float* b1  = (const float*)d_in[4];
  const float* Wq1 = (const float*)d_in[5];
  const float* Wk1 = (const float*)d_in[6];
  const float* Wv1 = (const float*)d_in[7];
  const float* Wo1 = (const float*)d_in[8];
  const float* g2  = (const float*)d_in[9];
  const float* b2  = (const float*)d_in[10];
  const float* cg  = (const float*)d_in[11];
  const float* cb  = (const float*)d_in[12];
  const float* Wq2 = (const float*)d_in[13];
  const float* Wk2 = (const float*)d_in[14];
  const float* Wv2 = (const float*)d_in[15];
  const float* Wo2 = (const float*)d_in[16];

  char* ws = (char*)d_ws;
  unsigned short* W1t  = (unsigned short*)(ws + 0);
  unsigned short* Wo1t = (unsigned short*)(ws + 393216);
  unsigned short* W2t  = (unsigned short*)(ws + 524288);
  unsigned short* Wo2t = (unsigned short*)(ws + 917504);
  float* ropeC         = (float*)(ws + 1048576);
  float* ropeS         = (float*)(ws + 1050624);

  if (ws_size >= 118493184u) {
    // -------- GEMM pipeline. Layout (118.5 MB): --------
    unsigned short* xt_bf  = (unsigned short*)(ws + 1052672);
    unsigned short* xnA    = (unsigned short*)(ws + 34607104);
    unsigned short* xnB    = (unsigned short*)(ws + 51384320);
    unsigned short* qkv    = (unsigned short*)(ws + 68161536);
    unsigned short* aout   = xnA;        // alias: xnA dead when aout live
    unsigned short* rows2  = xt_bf;      // xt raw dead after gemm_out#1
    float* xs1             = (float*)d_out;
    float* outp            = (float*)d_out;

    prep_all<<<4097, 256, 0, stream>>>(x, mm, g1, b1, cg, cb, xt_bf, xnA, xnB,
                                       Wq1, Wk1, Wv1, Wo1, Wq2, Wk2, Wv2, Wo2,
                                       W1t, Wo1t, W2t, Wo2t, ropeC, ropeS);
    // stage 1: q,k,v all from xn1
    gemm_qkv<<<dim3(256, 6), 256, 0, stream>>>(xnA, xnA, W1t, qkv, ropeC, ropeS);
    attn_seq<<<512, 256, 0, stream>>>(qkv, pb, aout);
    gemm_out<<<dim3(256, 2), 256, 0, stream>>>(aout, Wo1t, xt_bf, nullptr, xs1, nullptr);
    // stage 2: q from LN(xs1), k/v from ctx
    ln_rows<<<512, 256, 0, stream>>>(xs1, g2, b2, xnA);
    gemm_qkv<<<dim3(256, 6), 256, 0, stream>>>(xnA, xnB, W2t, qkv, ropeC, ropeS);
    attn_seq<<<512, 256, 0, stream>>>(qkv, pb, aout);
    gemm_out<<<dim3(256, 2), 256, 0, stream>>>(aout, Wo2t, nullptr, xs1, nullptr, rows2);
    transpose_out<<<1024, 256, 0, stream>>>(rows2, outp, 0);
  } else {
    // -------- Fallback: round-8 verified fused pipeline (68.2 MB) --------
    float* xt  = (float*)(ws + 1052672);
    float* mmt = (float*)(ws + 34607104);
    float* xs1 = (float*)d_out;
    float* outp = (float*)d_out;

    prep_w<<<2049, 256, 0, stream>>>(Wq1, Wk1, Wv1, Wo1, Wq2, Wk2, Wv2, Wo2,
                                     W1t, Wo1t, W2t, Wo2t, ropeC, ropeS);
    transpose_in<<<2048, 256, 0, stream>>>(x, mm, xt, mmt);
    fused_stage<<<2048, 256, 0, stream>>>(xt, xt, xs1, g1, b1, g1, b1,
                                          W1t, Wo1t, ropeC, ropeS, pb, 0);
    fused_stage<<<2048, 256, 0, stream>>>(xs1, mmt, xt, g2, b2, cg, cb,
                                          W2t, Wo2t, ropeC, ropeS, pb, 1);
    transpose_out<<<1024, 256, 0, stream>>>(xt, outp, 1);
  }
}